// Round 6
// baseline (2909.070 us; speedup 1.0000x reference)
//
#include <hip/hip_runtime.h>
#include <cstdint>

#define BB 4
#define CC 512
#define DD 64
#define NN 4096
#define QTS 8

typedef unsigned short u16;

__device__ __forceinline__ float bf2f(u16 u) {
  union { unsigned int i; float f; } v; v.i = ((unsigned int)u) << 16; return v.f;
}
__device__ __forceinline__ u16 f2bf(float f) {
  unsigned int x = __float_as_uint(f);
  if ((x & 0x7fffffffu) > 0x7f800000u) return (u16)0x7fc0;
  return (u16)((x + 0x7fffu + ((x >> 16) & 1u)) >> 16);
}

// out[b][o][n] = bias[o] + sum_c W[o][c] * x[b][c][n]   (f32 in, bf16 out)
__global__ __launch_bounds__(256) void proj_kernel(
    const float* __restrict__ W, const float* __restrict__ bias,
    const float* __restrict__ X, u16* __restrict__ out, int O)
{
  const int b = blockIdx.z;
  const int o0 = blockIdx.y << 6;
  const int n0 = blockIdx.x << 6;
  const int t = threadIdx.x;
  const int tx = t & 15, ty = t >> 4;
  __shared__ float Wt[32][65];
  __shared__ float Xt[32][64];
  float acc[4][4];
#pragma unroll
  for (int i = 0; i < 4; ++i) {
    float bv = bias[o0 + ty * 4 + i];
    acc[i][0] = bv; acc[i][1] = bv; acc[i][2] = bv; acc[i][3] = bv;
  }
  const float* Xb = X + (size_t)b * CC * NN;
  for (int c0 = 0; c0 < CC; c0 += 32) {
#pragma unroll
    for (int i = 0; i < 8; ++i) {
      int lin = t + (i << 8);
      int c = lin & 31, o = lin >> 5;
      Wt[c][o] = W[(o0 + o) * CC + c0 + c];
    }
#pragma unroll
    for (int i = 0; i < 8; ++i) {
      int lin = t + (i << 8);
      int c = lin >> 6, n = lin & 63;
      Xt[c][n] = Xb[(c0 + c) * NN + n0 + n];
    }
    __syncthreads();
#pragma unroll
    for (int c = 0; c < 32; ++c) {
      float4 xv = *(const float4*)&Xt[c][tx * 4];
#pragma unroll
      for (int i = 0; i < 4; ++i) {
        float wv = Wt[c][ty * 4 + i];
        acc[i][0] += wv * xv.x; acc[i][1] += wv * xv.y;
        acc[i][2] += wv * xv.z; acc[i][3] += wv * xv.w;
      }
    }
    __syncthreads();
  }
  u16* ob = out + ((size_t)b * O + o0) * NN;
#pragma unroll
  for (int i = 0; i < 4; ++i) {
    ushort4 s;
    s.x = f2bf(acc[i][0]); s.y = f2bf(acc[i][1]);
    s.z = f2bf(acc[i][2]); s.w = f2bf(acc[i][3]);
    *(ushort4*)&ob[(ty * 4 + i) * NN + n0 + tx * 4] = s;
  }
}

// per-row online softmax stats for PAM: m (rowmax), 1/l (inv denom)
__global__ __launch_bounds__(256) void pam_stats_kernel(
    const u16* __restrict__ qp, const u16* __restrict__ kp,
    float* __restrict__ mP, float* __restrict__ lP)
{
  const int b = blockIdx.y;
  const int q0 = blockIdx.x * QTS;
  const int t = threadIdx.x;
  __shared__ float qs[64][QTS];
  __shared__ float ms[256], ss[256];
#pragma unroll
  for (int i = 0; i < (64 * QTS) / 256; ++i) {
    int lin = t + (i << 8);
    int d = lin / QTS, r = lin % QTS;
    qs[d][r] = bf2f(qp[(size_t)b * DD * NN + d * NN + q0 + r]);
  }
  __syncthreads();
  float m8[QTS], s8[QTS];
#pragma unroll
  for (int r = 0; r < QTS; ++r) { m8[r] = -1e30f; s8[r] = 0.f; }
  const u16* kpb = kp + (size_t)b * DD * NN;
  for (int ki = 0; ki < 16; ++ki) {
    int k = t + (ki << 8);
    float e8[QTS];
#pragma unroll
    for (int r = 0; r < QTS; ++r) e8[r] = 0.f;
#pragma unroll 8
    for (int d = 0; d < 64; ++d) {
      float kv = bf2f(kpb[d * NN + k]);
#pragma unroll
      for (int r = 0; r < QTS; ++r) e8[r] += qs[d][r] * kv;
    }
#pragma unroll
    for (int r = 0; r < QTS; ++r) {
      float mn = fmaxf(m8[r], e8[r]);
      s8[r] = s8[r] * __expf(m8[r] - mn) + __expf(e8[r] - mn);
      m8[r] = mn;
    }
  }
#pragma unroll 1
  for (int r = 0; r < QTS; ++r) {
    ms[t] = m8[r]; ss[t] = s8[r];
    __syncthreads();
    for (int w = 128; w > 0; w >>= 1) {
      if (t < w) {
        float m1 = ms[t], m2 = ms[t + w];
        float M = fmaxf(m1, m2);
        ss[t] = ss[t] * __expf(m1 - M) + ss[t + w] * __expf(m2 - M);
        ms[t] = M;
      }
      __syncthreads();
    }
    if (t == 0) { mP[b * NN + q0 + r] = ms[0]; lP[b * NN + q0 + r] = 1.f / ss[0]; }
    __syncthreads();
  }
}

// PAM PV + final epilogue: out(f32) = partial + gamma_p * (V @ attn^T) + x
__global__ __launch_bounds__(256) void pam_pv_final_kernel(
    const u16* __restrict__ qp, const u16* __restrict__ kp,
    const u16* __restrict__ vp, const float* __restrict__ mP,
    const float* __restrict__ lP, const float* __restrict__ gamma,
    const float* __restrict__ X, float* __restrict__ outp)
{
  const int b = blockIdx.z;
  const int q0 = blockIdx.y << 6;
  const int c0 = blockIdx.x << 7;
  const int t = threadIdx.x;
  const int tx = t & 15, ty = t >> 4;
  __shared__ float qt[64][64];   // [d][q]
  __shared__ float kt[64][32];   // [d][k]
  __shared__ float pt[32][64];   // [k][q]
  __shared__ float vt[32][132];  // [k][c] padded
  __shared__ float mls[64], rls[64];
  const u16* qpb = qp + (size_t)b * DD * NN;
  const u16* kpb = kp + (size_t)b * DD * NN;
  const u16* vpb = vp + (size_t)b * CC * NN;
#pragma unroll
  for (int i = 0; i < 16; ++i) {
    int lin = t + (i << 8);
    int d = lin >> 6, q = lin & 63;
    qt[d][q] = bf2f(qpb[d * NN + q0 + q]);
  }
  if (t < 64) { mls[t] = mP[b * NN + q0 + t]; rls[t] = lP[b * NN + q0 + t]; }
  __syncthreads();
  float m4[4], rl4[4];
#pragma unroll
  for (int qq = 0; qq < 4; ++qq) { m4[qq] = mls[tx * 4 + qq]; rl4[qq] = rls[tx * 4 + qq]; }
  float O[8][4];
#pragma unroll
  for (int i = 0; i < 8; ++i)
#pragma unroll
    for (int j = 0; j < 4; ++j) O[i][j] = 0.f;

  for (int k0 = 0; k0 < NN; k0 += 32) {
#pragma unroll
    for (int i = 0; i < 8; ++i) {
      int lin = t + (i << 8);
      int d = lin >> 5, kk = lin & 31;
      kt[d][kk] = bf2f(kpb[d * NN + k0 + kk]);
    }
#pragma unroll
    for (int i = 0; i < 16; ++i) {
      int lin = t + (i << 8);
      int c = lin >> 5, kk = lin & 31;
      vt[kk][c] = bf2f(vpb[(c0 + c) * NN + k0 + kk]);
    }
    __syncthreads();
#pragma unroll
    for (int kx = 0; kx < 2; ++kx) {
      int kk = ty * 2 + kx;
      float s0 = 0, s1 = 0, s2 = 0, s3 = 0;
#pragma unroll 16
      for (int d = 0; d < 64; ++d) {
        float kv = kt[d][kk];
        float4 qv = *(const float4*)&qt[d][tx * 4];
        s0 += qv.x * kv; s1 += qv.y * kv; s2 += qv.z * kv; s3 += qv.w * kv;
      }
      float4 pv;
      pv.x = __expf(s0 - m4[0]) * rl4[0];
      pv.y = __expf(s1 - m4[1]) * rl4[1];
      pv.z = __expf(s2 - m4[2]) * rl4[2];
      pv.w = __expf(s3 - m4[3]) * rl4[3];
      *(float4*)&pt[kk][tx * 4] = pv;
    }
    __syncthreads();
#pragma unroll 8
    for (int kk = 0; kk < 32; ++kk) {
      float4 pq = *(const float4*)&pt[kk][tx * 4];
      float4 va = *(const float4*)&vt[kk][ty * 8];
      float4 vb = *(const float4*)&vt[kk][ty * 8 + 4];
      float vv[8] = {va.x, va.y, va.z, va.w, vb.x, vb.y, vb.z, vb.w};
#pragma unroll
      for (int i = 0; i < 8; ++i) {
        O[i][0] += vv[i] * pq.x; O[i][1] += vv[i] * pq.y;
        O[i][2] += vv[i] * pq.z; O[i][3] += vv[i] * pq.w;
      }
    }
    __syncthreads();
  }
  float g = gamma[0];
  float* ob = outp + ((size_t)b * CC + c0) * NN;
  const float* xpb = X + ((size_t)b * CC + c0) * NN;
#pragma unroll
  for (int i = 0; i < 8; ++i) {
    size_t off = (size_t)(ty * 8 + i) * NN + q0 + tx * 4;
    float4 part = *(const float4*)&ob[off];
    float4 xv = *(const float4*)&xpb[off];
    float4 r;
    r.x = part.x + g * O[i][0] + xv.x;
    r.y = part.y + g * O[i][1] + xv.y;
    r.z = part.z + g * O[i][2] + xv.z;
    r.w = part.w + g * O[i][3] + xv.w;
    *(float4*)&ob[off] = r;
  }
}

// CAM energy: e[b][ci][cj] = dot over 512 of q/k viewed as [512][512]
__global__ __launch_bounds__(256) void cam_energy_kernel(
    const u16* __restrict__ qc, const u16* __restrict__ kc, float* __restrict__ eC)
{
  const int b = blockIdx.z;
  const int i0 = blockIdx.y << 6;
  const int j0 = blockIdx.x << 6;
  const int t = threadIdx.x;
  const int tx = t & 15, ty = t >> 4;
  __shared__ float At[32][68];
  __shared__ float Bt[32][68];
  const u16* qb = qc + (size_t)b * CC * CC;
  const u16* kb = kc + (size_t)b * CC * CC;
  float o[4][4];
#pragma unroll
  for (int i = 0; i < 4; ++i)
#pragma unroll
    for (int j = 0; j < 4; ++j) o[i][j] = 0.f;
  for (int m0 = 0; m0 < CC; m0 += 32) {
#pragma unroll
    for (int i = 0; i < 8; ++i) {
      int lin = t + (i << 8);
      int ci = lin >> 5, m = lin & 31;
      At[m][ci] = bf2f(qb[(i0 + ci) * CC + m0 + m]);
      Bt[m][ci] = bf2f(kb[(j0 + ci) * CC + m0 + m]);
    }
    __syncthreads();
#pragma unroll
    for (int m = 0; m < 32; ++m) {
      float4 a = *(const float4*)&At[m][ty * 4];
      float4 bv = *(const float4*)&Bt[m][tx * 4];
      o[0][0] += a.x * bv.x; o[0][1] += a.x * bv.y; o[0][2] += a.x * bv.z; o[0][3] += a.x * bv.w;
      o[1][0] += a.y * bv.x; o[1][1] += a.y * bv.y; o[1][2] += a.y * bv.z; o[1][3] += a.y * bv.w;
      o[2][0] += a.z * bv.x; o[2][1] += a.z * bv.y; o[2][2] += a.z * bv.z; o[2][3] += a.z * bv.w;
      o[3][0] += a.w * bv.x; o[3][1] += a.w * bv.y; o[3][2] += a.w * bv.z; o[3][3] += a.w * bv.w;
    }
    __syncthreads();
  }
  float* eb = eC + (size_t)b * CC * CC;
#pragma unroll
  for (int i = 0; i < 4; ++i) {
    float4 v;
    v.x = o[i][0]; v.y = o[i][1]; v.z = o[i][2]; v.w = o[i][3];
    *(float4*)&eb[(i0 + ty * 4 + i) * CC + j0 + tx * 4] = v;
  }
}

// CAM softmax of (rowmax - e) == exp(rowmin - e)/sum, in place
__global__ __launch_bounds__(256) void cam_softmax_kernel(float* __restrict__ eC)
{
  const int b = blockIdx.y, ci = blockIdx.x;
  float* row = eC + ((size_t)b * CC + ci) * CC;
  const int t = threadIdx.x;
  float e0 = row[t], e1 = row[t + 256];
  __shared__ float red[256];
  red[t] = fminf(e0, e1);
  __syncthreads();
  for (int w = 128; w > 0; w >>= 1) {
    if (t < w) red[t] = fminf(red[t], red[t + w]);
    __syncthreads();
  }
  float rmin = red[0];
  __syncthreads();
  float p0 = __expf(rmin - e0), p1 = __expf(rmin - e1);
  red[t] = p0 + p1;
  __syncthreads();
  for (int w = 128; w > 0; w >>= 1) {
    if (t < w) red[t] += red[t + w];
    __syncthreads();
  }
  float inv = 1.f / red[0];
  row[t] = p0 * inv;
  row[t + 256] = p1 * inv;
}

// CAM PV partial: out(f32) = gamma_c * sum_d attn[c][d]*vc[d][n] + x
__global__ __launch_bounds__(256) void cam_pv_partial_kernel(
    const float* __restrict__ attn, const u16* __restrict__ vc,
    const float* __restrict__ gamma, const float* __restrict__ X,
    float* __restrict__ outp)
{
  const int b = blockIdx.z;
  const int c00 = blockIdx.y << 6;
  const int n0 = blockIdx.x << 6;
  const int t = threadIdx.x;
  const int tx = t & 15, ty = t >> 4;
  __shared__ float At[32][68];  // [d][c]
  __shared__ float Bt[32][64];  // [d][n]
  const float* Ab = attn + (size_t)b * CC * CC;
  const u16* Vb = vc + (size_t)b * CC * NN;
  float o[4][4];
#pragma unroll
  for (int i = 0; i < 4; ++i)
#pragma unroll
    for (int j = 0; j < 4; ++j) o[i][j] = 0.f;
  for (int d0 = 0; d0 < CC; d0 += 32) {
#pragma unroll
    for (int i = 0; i < 8; ++i) {
      int lin = t + (i << 8);
      int c = lin >> 5, d = lin & 31;
      At[d][c] = Ab[(c00 + c) * CC + d0 + d];
    }
#pragma unroll
    for (int i = 0; i < 8; ++i) {
      int lin = t + (i << 8);
      int d = lin >> 6, n = lin & 63;
      Bt[d][n] = bf2f(Vb[(d0 + d) * NN + n0 + n]);
    }
    __syncthreads();
#pragma unroll
    for (int d = 0; d < 32; ++d) {
      float4 a = *(const float4*)&At[d][ty * 4];
      float4 bv = *(const float4*)&Bt[d][tx * 4];
      o[0][0] += a.x * bv.x; o[0][1] += a.x * bv.y; o[0][2] += a.x * bv.z; o[0][3] += a.x * bv.w;
      o[1][0] += a.y * bv.x; o[1][1] += a.y * bv.y; o[1][2] += a.y * bv.z; o[1][3] += a.y * bv.w;
      o[2][0] += a.z * bv.x; o[2][1] += a.z * bv.y; o[2][2] += a.z * bv.z; o[2][3] += a.z * bv.w;
      o[3][0] += a.w * bv.x; o[3][1] += a.w * bv.y; o[3][2] += a.w * bv.z; o[3][3] += a.w * bv.w;
    }
    __syncthreads();
  }
  float g = gamma[0];
  const float* xpb = X + ((size_t)b * CC + c00) * NN;
  float* opb = outp + ((size_t)b * CC + c00) * NN;
#pragma unroll
  for (int i = 0; i < 4; ++i) {
    size_t off = (size_t)(ty * 4 + i) * NN + n0 + tx * 4;
    float4 xv = *(const float4*)&xpb[off];
    float4 r;
    r.x = g * o[i][0] + xv.x;
    r.y = g * o[i][1] + xv.y;
    r.z = g * o[i][2] + xv.z;
    r.w = g * o[i][3] + xv.w;
    *(float4*)&opb[off] = r;
  }
}

extern "C" void kernel_launch(void* const* d_in, const int* in_sizes, int n_in,
                              void* d_out, int out_size, void* d_ws, size_t ws_size,
                              hipStream_t stream) {
  const float* x   = (const float*)d_in[0];
  const float* pwq = (const float*)d_in[1];
  const float* pbq = (const float*)d_in[2];
  const float* pwk = (const float*)d_in[3];
  const float* pbk = (const float*)d_in[4];
  const float* pwv = (const float*)d_in[5];
  const float* pbv = (const float*)d_in[6];
  const float* pgam= (const float*)d_in[7];
  const float* cwq = (const float*)d_in[8];
  const float* cbq = (const float*)d_in[9];
  const float* cwk = (const float*)d_in[10];
  const float* cbk = (const float*)d_in[11];
  const float* cwv = (const float*)d_in[12];
  const float* cbv = (const float*)d_in[13];
  const float* cgam= (const float*)d_in[14];
  float* out = (float*)d_out;

  const size_t SMALL = (size_t)BB * DD * NN;   // 1,048,576 elems
  const size_t BIG   = (size_t)BB * CC * NN;   // 8,388,608 elems
  // compact workspace (~25.3 MB): one shared buffer set, CAM phase then PAM phase
  u16* vbuf = (u16*)d_ws;            // BIG   (16.8 MB)
  u16* qbuf = vbuf + BIG;            // SMALL (2.1 MB)
  u16* kbuf = qbuf + SMALL;          // SMALL (2.1 MB)
  float* eC = (float*)(kbuf + SMALL);// BB*CC*CC f32 (4.2 MB)
  float* mP = eC + (size_t)BB * CC * CC;  // 64 KB
  float* lP = mP + (size_t)BB * NN;       // 64 KB

  dim3 blk(256);
  // ---- CAM phase: d_out <- gamma_c*outC + x ----
  proj_kernel<<<dim3(64, 1, BB), blk, 0, stream>>>(cwq, cbq, x, qbuf, DD);
  proj_kernel<<<dim3(64, 1, BB), blk, 0, stream>>>(cwk, cbk, x, kbuf, DD);
  proj_kernel<<<dim3(64, 8, BB), blk, 0, stream>>>(cwv, cbv, x, vbuf, CC);
  cam_energy_kernel<<<dim3(8, 8, BB), blk, 0, stream>>>(qbuf, kbuf, eC);
  cam_softmax_kernel<<<dim3(CC, BB), blk, 0, stream>>>(eC);
  cam_pv_partial_kernel<<<dim3(64, 8, BB), blk, 0, stream>>>(eC, vbuf, cgam, x, out);
  // ---- PAM phase (reuses buffers): d_out <- partial + gamma_p*outP + x ----
  proj_kernel<<<dim3(64, 1, BB), blk, 0, stream>>>(pwq, pbq, x, qbuf, DD);
  proj_kernel<<<dim3(64, 1, BB), blk, 0, stream>>>(pwk, pbk, x, kbuf, DD);
  proj_kernel<<<dim3(64, 8, BB), blk, 0, stream>>>(pwv, pbv, x, vbuf, CC);
  pam_stats_kernel<<<dim3(NN / QTS, BB), blk, 0, stream>>>(qbuf, kbuf, mP, lP);
  pam_pv_final_kernel<<<dim3(4, 64, BB), blk, 0, stream>>>(qbuf, kbuf, vbuf, mP, lP, pgam, x, out);
}

// Round 7
// 832.990 us; speedup vs baseline: 3.4923x; 3.4923x over previous
//
#include <hip/hip_runtime.h>
#include <cstdint>

#define BB 4
#define CC 512
#define DD 64
#define NN 4096

typedef unsigned short u16;
typedef __attribute__((ext_vector_type(8))) short bf16x8;
typedef __attribute__((ext_vector_type(4))) float f32x4;
typedef __attribute__((ext_vector_type(8))) unsigned short us8;

__device__ __forceinline__ float bf2f(u16 u) {
  union { unsigned int i; float f; } v; v.i = ((unsigned int)u) << 16; return v.f;
}
__device__ __forceinline__ u16 f2bf(float f) {
  unsigned int x = __float_as_uint(f);
  if ((x & 0x7fffffffu) > 0x7f800000u) return (u16)0x7fc0;
  return (u16)((x + 0x7fffu + ((x >> 16) & 1u)) >> 16);
}

// out[b][o][n] = bias[o] + sum_c W[o][c] * x[b][c][n]   (f32 in, bf16 out)
__global__ __launch_bounds__(256) void proj_kernel(
    const float* __restrict__ W, const float* __restrict__ bias,
    const float* __restrict__ X, u16* __restrict__ out, int O)
{
  const int b = blockIdx.z;
  const int o0 = blockIdx.y << 6;
  const int n0 = blockIdx.x << 6;
  const int t = threadIdx.x;
  const int tx = t & 15, ty = t >> 4;
  __shared__ float Wt[32][65];
  __shared__ float Xt[32][64];
  float acc[4][4];
#pragma unroll
  for (int i = 0; i < 4; ++i) {
    float bv = bias[o0 + ty * 4 + i];
    acc[i][0] = bv; acc[i][1] = bv; acc[i][2] = bv; acc[i][3] = bv;
  }
  const float* Xb = X + (size_t)b * CC * NN;
  for (int c0 = 0; c0 < CC; c0 += 32) {
#pragma unroll
    for (int i = 0; i < 8; ++i) {
      int lin = t + (i << 8);
      int c = lin & 31, o = lin >> 5;
      Wt[c][o] = W[(o0 + o) * CC + c0 + c];
    }
#pragma unroll
    for (int i = 0; i < 8; ++i) {
      int lin = t + (i << 8);
      int c = lin >> 6, n = lin & 63;
      Xt[c][n] = Xb[(c0 + c) * NN + n0 + n];
    }
    __syncthreads();
#pragma unroll
    for (int c = 0; c < 32; ++c) {
      float4 xv = *(const float4*)&Xt[c][tx * 4];
#pragma unroll
      for (int i = 0; i < 4; ++i) {
        float wv = Wt[c][ty * 4 + i];
        acc[i][0] += wv * xv.x; acc[i][1] += wv * xv.y;
        acc[i][2] += wv * xv.z; acc[i][3] += wv * xv.w;
      }
    }
    __syncthreads();
  }
  u16* ob = out + ((size_t)b * O + o0) * NN;
#pragma unroll
  for (int i = 0; i < 4; ++i) {
    ushort4 s;
    s.x = f2bf(acc[i][0]); s.y = f2bf(acc[i][1]);
    s.z = f2bf(acc[i][2]); s.w = f2bf(acc[i][3]);
    *(ushort4*)&ob[(ty * 4 + i) * NN + n0 + tx * 4] = s;
  }
}

// PAM pass1+2 merged: MFMA S^T = K^T Q, online row-stats in regs, then write
// P[q][k] = exp(S - m) / l  as bf16. Block: 128 thr (2 waves), q-tile 32.
__global__ __launch_bounds__(128) void pam_p_kernel(
    const u16* __restrict__ qp, const u16* __restrict__ kp,
    u16* __restrict__ P, int bbase)
{
  const int b = bbase + blockIdx.y;
  const int q0 = blockIdx.x * 32;
  const int t = threadIdx.x;
  const int lane = t & 63, wid = t >> 6;
  const int g = lane >> 4, l15 = lane & 15;
  __shared__ __align__(16) u16 QTs[32][88];   // [q][d] transposed
  __shared__ __align__(16) u16 KTs[128][88];  // [k][d] transposed
  const u16* qpb = qp + (size_t)b * DD * NN;
  const u16* kpb = kp + (size_t)b * DD * NN;
  u16* Pb = P + (size_t)blockIdx.y * NN * NN;

  // stage QTs (d-pair packed u32 writes; 128 pair-chunks, 1 per thread)
  {
    int d = 2 * (t & 31);
    int q8 = (t >> 5) * 8;
    us8 v0 = *(const us8*)&qpb[(size_t)d * NN + q0 + q8];
    us8 v1 = *(const us8*)&qpb[(size_t)(d + 1) * NN + q0 + q8];
#pragma unroll
    for (int j = 0; j < 8; ++j)
      *(uint32_t*)&QTs[q8 + j][d] = (uint32_t)v0[j] | ((uint32_t)v1[j] << 16);
  }

  float m_run = -3e38f, s_run = 0.f;
  // ---- pass 1: stats ----
  for (int k0 = 0; k0 < NN; k0 += 128) {
#pragma unroll
    for (int i = 0; i < 4; ++i) {
      int idx = t + 128 * i;
      int d = 2 * (idx & 31);
      int k8 = (idx >> 5) * 8;
      us8 v0 = *(const us8*)&kpb[(size_t)d * NN + k0 + k8];
      us8 v1 = *(const us8*)&kpb[(size_t)(d + 1) * NN + k0 + k8];
#pragma unroll
      for (int j = 0; j < 8; ++j)
        *(uint32_t*)&KTs[k8 + j][d] = (uint32_t)v0[j] | ((uint32_t)v1[j] << 16);
    }
    __syncthreads();
#pragma unroll
    for (int mt = 0; mt < 8; ++mt) {
      f32x4 acc = {0.f, 0.f, 0.f, 0.f};
#pragma unroll
      for (int ks = 0; ks < 2; ++ks) {
        bf16x8 a = *(const bf16x8*)&KTs[16 * mt + l15][32 * ks + 8 * g];
        bf16x8 bq = *(const bf16x8*)&QTs[16 * wid + l15][32 * ks + 8 * g];
        acc = __builtin_amdgcn_mfma_f32_16x16x32_bf16(a, bq, acc, 0, 0, 0);
      }
      float mx = fmaxf(fmaxf(acc[0], acc[1]), fmaxf(acc[2], acc[3]));
      float mn = fmaxf(m_run, mx);
      s_run = s_run * __expf(m_run - mn) + __expf(acc[0] - mn) + __expf(acc[1] - mn)
            + __expf(acc[2] - mn) + __expf(acc[3] - mn);
      m_run = mn;
    }
    __syncthreads();
  }
  // merge the 4 g-group partials of column q (lanes l, l^16, l^32, l^48)
#pragma unroll
  for (int off = 16; off <= 32; off <<= 1) {
    float mo = __shfl_xor(m_run, off);
    float so = __shfl_xor(s_run, off);
    float mn = fmaxf(m_run, mo);
    s_run = s_run * __expf(m_run - mn) + so * __expf(mo - mn);
    m_run = mn;
  }
  float rl = 1.f / s_run;

  // ---- pass 2: write P ----
  for (int k0 = 0; k0 < NN; k0 += 128) {
#pragma unroll
    for (int i = 0; i < 4; ++i) {
      int idx = t + 128 * i;
      int d = 2 * (idx & 31);
      int k8 = (idx >> 5) * 8;
      us8 v0 = *(const us8*)&kpb[(size_t)d * NN + k0 + k8];
      us8 v1 = *(const us8*)&kpb[(size_t)(d + 1) * NN + k0 + k8];
#pragma unroll
      for (int j = 0; j < 8; ++j)
        *(uint32_t*)&KTs[k8 + j][d] = (uint32_t)v0[j] | ((uint32_t)v1[j] << 16);
    }
    __syncthreads();
#pragma unroll
    for (int mt = 0; mt < 8; ++mt) {
      f32x4 acc = {0.f, 0.f, 0.f, 0.f};
#pragma unroll
      for (int ks = 0; ks < 2; ++ks) {
        bf16x8 a = *(const bf16x8*)&KTs[16 * mt + l15][32 * ks + 8 * g];
        bf16x8 bq = *(const bf16x8*)&QTs[16 * wid + l15][32 * ks + 8 * g];
        acc = __builtin_amdgcn_mfma_f32_16x16x32_bf16(a, bq, acc, 0, 0, 0);
      }
      u16 p0 = f2bf(__expf(acc[0] - m_run) * rl);
      u16 p1 = f2bf(__expf(acc[1] - m_run) * rl);
      u16 p2 = f2bf(__expf(acc[2] - m_run) * rl);
      u16 p3 = f2bf(__expf(acc[3] - m_run) * rl);
      uint2 pk;
      pk.x = (uint32_t)p0 | ((uint32_t)p1 << 16);
      pk.y = (uint32_t)p2 | ((uint32_t)p3 << 16);
      *(uint2*)&Pb[(size_t)(q0 + 16 * wid + l15) * NN + k0 + 16 * mt + 4 * g] = pk;
    }
    __syncthreads();
  }
}

// PAM PV GEMM: out[b][c][q] += gamma * sum_k V[c][k] P[q][k] + x  (fused epilogue)
// 128x128 tile, K-step 64, 4 waves in 2x2 grid.
__global__ __launch_bounds__(256) void pam_gemm_kernel(
    const u16* __restrict__ vp, const u16* __restrict__ P,
    const float* __restrict__ gamma, const float* __restrict__ X,
    float* __restrict__ out, int bbase)
{
  const int b = bbase + blockIdx.z;
  const int c0 = blockIdx.y * 128;
  const int q0 = blockIdx.x * 128;
  const int t = threadIdx.x;
  const int lane = t & 63, wid = t >> 6;
  const int g = lane >> 4, l15 = lane & 15;
  const int wm = (wid >> 1) * 64, wn = (wid & 1) * 64;
  __shared__ __align__(16) u16 VT[128][88];  // [c][k]
  __shared__ __align__(16) u16 PT[128][88];  // [q][k]
  const u16* Vb = vp + (size_t)b * CC * NN;
  const u16* Pb = P + (size_t)blockIdx.z * NN * NN;
  f32x4 acc[4][4] = {};
  for (int k0 = 0; k0 < NN; k0 += 64) {
#pragma unroll
    for (int i = 0; i < 4; ++i) {
      int idx = t + 256 * i;
      int r = idx >> 3, k8 = (idx & 7) * 8;
      *(us8*)&VT[r][k8] = *(const us8*)&Vb[(size_t)(c0 + r) * NN + k0 + k8];
      *(us8*)&PT[r][k8] = *(const us8*)&Pb[(size_t)(q0 + r) * NN + k0 + k8];
    }
    __syncthreads();
#pragma unroll
    for (int ks = 0; ks < 2; ++ks) {
      bf16x8 af[4], bf[4];
#pragma unroll
      for (int mt = 0; mt < 4; ++mt)
        af[mt] = *(const bf16x8*)&VT[wm + 16 * mt + l15][32 * ks + 8 * g];
#pragma unroll
      for (int nt = 0; nt < 4; ++nt)
        bf[nt] = *(const bf16x8*)&PT[wn + 16 * nt + l15][32 * ks + 8 * g];
#pragma unroll
      for (int mt = 0; mt < 4; ++mt)
#pragma unroll
        for (int nt = 0; nt < 4; ++nt)
          acc[mt][nt] = __builtin_amdgcn_mfma_f32_16x16x32_bf16(
              af[mt], bf[nt], acc[mt][nt], 0, 0, 0);
    }
    __syncthreads();
  }
  const float gv = gamma[0];
#pragma unroll
  for (int mt = 0; mt < 4; ++mt) {
    int c = c0 + wm + 16 * mt + 4 * g;
#pragma unroll
    for (int r = 0; r < 4; ++r) {
      size_t rowoff = ((size_t)b * CC + c + r) * NN;
#pragma unroll
      for (int nt = 0; nt < 4; ++nt) {
        size_t off = rowoff + q0 + wn + 16 * nt + l15;
        out[off] += gv * acc[mt][nt][r] + X[off];
      }
    }
  }
}

// CAM energy: e[b][ci][cj] = dot over 512 of q/k viewed as [512][512]
__global__ __launch_bounds__(256) void cam_energy_kernel(
    const u16* __restrict__ qc, const u16* __restrict__ kc, float* __restrict__ eC)
{
  const int b = blockIdx.z;
  const int i0 = blockIdx.y << 6;
  const int j0 = blockIdx.x << 6;
  const int t = threadIdx.x;
  const int tx = t & 15, ty = t >> 4;
  __shared__ float At[32][68];
  __shared__ float Bt[32][68];
  const u16* qb = qc + (size_t)b * CC * CC;
  const u16* kb = kc + (size_t)b * CC * CC;
  float o[4][4];
#pragma unroll
  for (int i = 0; i < 4; ++i)
#pragma unroll
    for (int j = 0; j < 4; ++j) o[i][j] = 0.f;
  for (int m0 = 0; m0 < CC; m0 += 32) {
#pragma unroll
    for (int i = 0; i < 8; ++i) {
      int lin = t + (i << 8);
      int ci = lin >> 5, m = lin & 31;
      At[m][ci] = bf2f(qb[(i0 + ci) * CC + m0 + m]);
      Bt[m][ci] = bf2f(kb[(j0 + ci) * CC + m0 + m]);
    }
    __syncthreads();
#pragma unroll
    for (int m = 0; m < 32; ++m) {
      float4 a = *(const float4*)&At[m][ty * 4];
      float4 bv = *(const float4*)&Bt[m][tx * 4];
      o[0][0] += a.x * bv.x; o[0][1] += a.x * bv.y; o[0][2] += a.x * bv.z; o[0][3] += a.x * bv.w;
      o[1][0] += a.y * bv.x; o[1][1] += a.y * bv.y; o[1][2] += a.y * bv.z; o[1][3] += a.y * bv.w;
      o[2][0] += a.z * bv.x; o[2][1] += a.z * bv.y; o[2][2] += a.z * bv.z; o[2][3] += a.z * bv.w;
      o[3][0] += a.w * bv.x; o[3][1] += a.w * bv.y; o[3][2] += a.w * bv.z; o[3][3] += a.w * bv.w;
    }
    __syncthreads();
  }
  float* eb = eC + (size_t)b * CC * CC;
#pragma unroll
  for (int i = 0; i < 4; ++i) {
    float4 v;
    v.x = o[i][0]; v.y = o[i][1]; v.z = o[i][2]; v.w = o[i][3];
    *(float4*)&eb[(i0 + ty * 4 + i) * CC + j0 + tx * 4] = v;
  }
}

// CAM softmax of (rowmax - e) == exp(rowmin - e)/sum, in place
__global__ __launch_bounds__(256) void cam_softmax_kernel(float* __restrict__ eC)
{
  const int b = blockIdx.y, ci = blockIdx.x;
  float* row = eC + ((size_t)b * CC + ci) * CC;
  const int t = threadIdx.x;
  float e0 = row[t], e1 = row[t + 256];
  __shared__ float red[256];
  red[t] = fminf(e0, e1);
  __syncthreads();
  for (int w = 128; w > 0; w >>= 1) {
    if (t < w) red[t] = fminf(red[t], red[t + w]);
    __syncthreads();
  }
  float rmin = red[0];
  __syncthreads();
  float p0 = __expf(rmin - e0), p1 = __expf(rmin - e1);
  red[t] = p0 + p1;
  __syncthreads();
  for (int w = 128; w > 0; w >>= 1) {
    if (t < w) red[t] += red[t + w];
    __syncthreads();
  }
  float inv = 1.f / red[0];
  row[t] = p0 * inv;
  row[t + 256] = p1 * inv;
}

// CAM PV partial: out(f32) = gamma_c * sum_d attn[c][d]*vc[d][n] + x
__global__ __launch_bounds__(256) void cam_pv_partial_kernel(
    const float* __restrict__ attn, const u16* __restrict__ vc,
    const float* __restrict__ gamma, const float* __restrict__ X,
    float* __restrict__ outp)
{
  const int b = blockIdx.z;
  const int c00 = blockIdx.y << 6;
  const int n0 = blockIdx.x << 6;
  const int t = threadIdx.x;
  const int tx = t & 15, ty = t >> 4;
  __shared__ float At[32][68];  // [d][c]
  __shared__ float Bt[32][64];  // [d][n]
  const float* Ab = attn + (size_t)b * CC * CC;
  const u16* Vb = vc + (size_t)b * CC * NN;
  float o[4][4];
#pragma unroll
  for (int i = 0; i < 4; ++i)
#pragma unroll
    for (int j = 0; j < 4; ++j) o[i][j] = 0.f;
  for (int d0 = 0; d0 < CC; d0 += 32) {
#pragma unroll
    for (int i = 0; i < 8; ++i) {
      int lin = t + (i << 8);
      int c = lin >> 5, d = lin & 31;
      At[d][c] = Ab[(c00 + c) * CC + d0 + d];
    }
#pragma unroll
    for (int i = 0; i < 8; ++i) {
      int lin = t + (i << 8);
      int d = lin >> 6, n = lin & 63;
      Bt[d][n] = bf2f(Vb[(d0 + d) * NN + n0 + n]);
    }
    __syncthreads();
#pragma unroll
    for (int d = 0; d < 32; ++d) {
      float4 a = *(const float4*)&At[d][ty * 4];
      float4 bv = *(const float4*)&Bt[d][tx * 4];
      o[0][0] += a.x * bv.x; o[0][1] += a.x * bv.y; o[0][2] += a.x * bv.z; o[0][3] += a.x * bv.w;
      o[1][0] += a.y * bv.x; o[1][1] += a.y * bv.y; o[1][2] += a.y * bv.z; o[1][3] += a.y * bv.w;
      o[2][0] += a.z * bv.x; o[2][1] += a.z * bv.y; o[2][2] += a.z * bv.z; o[2][3] += a.z * bv.w;
      o[3][0] += a.w * bv.x; o[3][1] += a.w * bv.y; o[3][2] += a.w * bv.z; o[3][3] += a.w * bv.w;
    }
    __syncthreads();
  }
  float g = gamma[0];
  const float* xpb = X + ((size_t)b * CC + c00) * NN;
  float* opb = outp + ((size_t)b * CC + c00) * NN;
#pragma unroll
  for (int i = 0; i < 4; ++i) {
    size_t off = (size_t)(ty * 4 + i) * NN + n0 + tx * 4;
    float4 xv = *(const float4*)&xpb[off];
    float4 r;
    r.x = g * o[i][0] + xv.x;
    r.y = g * o[i][1] + xv.y;
    r.z = g * o[i][2] + xv.z;
    r.w = g * o[i][3] + xv.w;
    *(float4*)&opb[off] = r;
  }
}

extern "C" void kernel_launch(void* const* d_in, const int* in_sizes, int n_in,
                              void* d_out, int out_size, void* d_ws, size_t ws_size,
                              hipStream_t stream) {
  const float* x   = (const float*)d_in[0];
  const float* pwq = (const float*)d_in[1];
  const float* pbq = (const float*)d_in[2];
  const float* pwk = (const float*)d_in[3];
  const float* pbk = (const float*)d_in[4];
  const float* pwv = (const float*)d_in[5];
  const float* pbv = (const float*)d_in[6];
  const float* pgam= (const float*)d_in[7];
  const float* cwq = (const float*)d_in[8];
  const float* cbq = (const float*)d_in[9];
  const float* cwk = (const float*)d_in[10];
  const float* cbk = (const float*)d_in[11];
  const float* cwv = (const float*)d_in[12];
  const float* cbv = (const float*)d_in[13];
  const float* cgam= (const float*)d_in[14];
  float* out = (float*)d_out;

  const size_t SMALL = (size_t)BB * DD * NN;   // 1,048,576 elems
  const size_t BIG   = (size_t)BB * CC * NN;   // 8,388,608 elems
  u16* vbuf = (u16*)d_ws;             // 16.8 MB
  u16* qbuf = vbuf + BIG;             // 2.1 MB
  u16* kbuf = qbuf + SMALL;           // 2.1 MB
  float* eC = (float*)(kbuf + SMALL); // 4.2 MB
  u16* Pws = (u16*)(eC + (size_t)BB * CC * CC);
  size_t fixed = (size_t)((char*)Pws - (char*)d_ws);
  int NB = 1;  // batches of P materialized at once (33.6 MB each)
  if (ws_size >= fixed + 4ull * NN * NN * 2) NB = 4;
  else if (ws_size >= fixed + 2ull * NN * NN * 2) NB = 2;

  dim3 blk(256);
  // ---- CAM phase: d_out <- gamma_c*outC + x ----
  proj_kernel<<<dim3(64, 1, BB), blk, 0, stream>>>(cwq, cbq, x, qbuf, DD);
  proj_kernel<<<dim3(64, 1, BB), blk, 0, stream>>>(cwk, cbk, x, kbuf, DD);
  proj_kernel<<<dim3(64, 8, BB), blk, 0, stream>>>(cwv, cbv, x, vbuf, CC);
  cam_energy_kernel<<<dim3(8, 8, BB), blk, 0, stream>>>(qbuf, kbuf, eC);
  cam_softmax_kernel<<<dim3(CC, BB), blk, 0, stream>>>(eC);
  cam_pv_partial_kernel<<<dim3(64, 8, BB), blk, 0, stream>>>(eC, vbuf, cgam, x, out);
  // ---- PAM phase: d_out += gamma_p*outP + x (MFMA path) ----
  proj_kernel<<<dim3(64, 1, BB), blk, 0, stream>>>(pwq, pbq, x, qbuf, DD);
  proj_kernel<<<dim3(64, 1, BB), blk, 0, stream>>>(pwk, pbk, x, kbuf, DD);
  proj_kernel<<<dim3(64, 8, BB), blk, 0, stream>>>(pwv, pbv, x, vbuf, CC);
  for (int bb = 0; bb < BB; bb += NB) {
    pam_p_kernel<<<dim3(NN / 32, NB), dim3(128), 0, stream>>>(qbuf, kbuf, Pws, bb);
    pam_gemm_kernel<<<dim3(NN / 128, CC / 128, NB), blk, 0, stream>>>(
        vbuf, Pws, pgam, x, out, bb);
  }
}

// Round 9
// 603.389 us; speedup vs baseline: 4.8212x; 1.3805x over previous
//
#include <hip/hip_runtime.h>
#include <cstdint>

#define BB 4
#define CC 512
#define DD 64
#define NN 4096
#define KCH 512

typedef unsigned short u16;
typedef __attribute__((ext_vector_type(8))) short bf16x8;
typedef __attribute__((ext_vector_type(4))) float f32x4;
typedef __attribute__((ext_vector_type(8))) unsigned short us8;

__device__ __forceinline__ float bf2f(u16 u) {
  union { unsigned int i; float f; } v; v.i = ((unsigned int)u) << 16; return v.f;
}
__device__ __forceinline__ u16 f2bf(float f) {
  unsigned int x = __float_as_uint(f);
  if ((x & 0x7fffffffu) > 0x7f800000u) return (u16)0x7fc0;
  return (u16)((x + 0x7fffu + ((x >> 16) & 1u)) >> 16);
}

__global__ __launch_bounds__(256) void zero_kernel(float* __restrict__ p, int n) {
  int i = blockIdx.x * 256 + threadIdx.x;
  if (i < n) p[i] = 0.f;
}

// SIMT projection (kept for CAM q/k, O=64): out[b][o][n] bf16
__global__ __launch_bounds__(256) void proj_kernel(
    const float* __restrict__ W, const float* __restrict__ bias,
    const float* __restrict__ X, u16* __restrict__ out, int O)
{
  const int b = blockIdx.z;
  const int o0 = blockIdx.y << 6;
  const int n0 = blockIdx.x << 6;
  const int t = threadIdx.x;
  const int tx = t & 15, ty = t >> 4;
  __shared__ float Wt[32][65];
  __shared__ float Xt[32][64];
  float acc[4][4];
#pragma unroll
  for (int i = 0; i < 4; ++i) {
    float bv = bias[o0 + ty * 4 + i];
    acc[i][0] = bv; acc[i][1] = bv; acc[i][2] = bv; acc[i][3] = bv;
  }
  const float* Xb = X + (size_t)b * CC * NN;
  for (int c0 = 0; c0 < CC; c0 += 32) {
#pragma unroll
    for (int i = 0; i < 8; ++i) {
      int lin = t + (i << 8);
      int c = lin & 31, o = lin >> 5;
      Wt[c][o] = W[(o0 + o) * CC + c0 + c];
    }
#pragma unroll
    for (int i = 0; i < 8; ++i) {
      int lin = t + (i << 8);
      int c = lin >> 6, n = lin & 63;
      Xt[c][n] = Xb[(c0 + c) * NN + n0 + n];
    }
    __syncthreads();
#pragma unroll
    for (int c = 0; c < 32; ++c) {
      float4 xv = *(const float4*)&Xt[c][tx * 4];
#pragma unroll
      for (int i = 0; i < 4; ++i) {
        float wv = Wt[c][ty * 4 + i];
        acc[i][0] += wv * xv.x; acc[i][1] += wv * xv.y;
        acc[i][2] += wv * xv.z; acc[i][3] += wv * xv.w;
      }
    }
    __syncthreads();
  }
  u16* ob = out + ((size_t)b * O + o0) * NN;
#pragma unroll
  for (int i = 0; i < 4; ++i) {
    ushort4 s;
    s.x = f2bf(acc[i][0]); s.y = f2bf(acc[i][1]);
    s.z = f2bf(acc[i][2]); s.w = f2bf(acc[i][3]);
    *(ushort4*)&ob[(ty * 4 + i) * NN + n0 + tx * 4] = s;
  }
}

// PAM q/k projection, MFMA, TRANSPOSED output: oT[b][n][64]
__global__ __launch_bounds__(256) void projT_mfma_kernel(
    const float* __restrict__ W, const float* __restrict__ bias,
    const float* __restrict__ X, u16* __restrict__ oT)
{
  const int b = blockIdx.z;
  const int n0 = blockIdx.x * 128;
  const int t = threadIdx.x;
  const int lane = t & 63, wid = t >> 6;
  const int g = lane >> 4, l15 = lane & 15;
  __shared__ __align__(16) u16 XT[128][72];  // [n][c-slice]
  __shared__ __align__(16) u16 WT[64][72];   // [o][c-slice]
  const float* Xb = X + (size_t)b * CC * NN;
  f32x4 acc[2][4] = {};
  for (int c0 = 0; c0 < CC; c0 += 64) {
#pragma unroll
    for (int i = 0; i < 4; ++i) {   // WT: 64o x 64c
      int idx = t + 256 * i;
      int o = idx >> 4, cq = (idx & 15) * 4;
      float4 w = *(const float4*)&W[(size_t)o * CC + c0 + cq];
      ushort4 s; s.x = f2bf(w.x); s.y = f2bf(w.y); s.z = f2bf(w.z); s.w = f2bf(w.w);
      *(ushort4*)&WT[o][cq] = s;
    }
#pragma unroll
    for (int i = 0; i < 4; ++i) {   // XT: 128n x 64c pack-pair transpose
      int idx = t + 256 * i;
      int n4 = (idx & 31) * 4, cp = idx >> 5;
      float4 v0 = *(const float4*)&Xb[(size_t)(c0 + 2 * cp) * NN + n0 + n4];
      float4 v1 = *(const float4*)&Xb[(size_t)(c0 + 2 * cp + 1) * NN + n0 + n4];
      float a0[4] = {v0.x, v0.y, v0.z, v0.w};
      float a1[4] = {v1.x, v1.y, v1.z, v1.w};
#pragma unroll
      for (int j = 0; j < 4; ++j) {
        int jr = (j + (idx & 31)) & 3;  // lane-rotated to spread LDS banks
        uint32_t pk = (uint32_t)f2bf(a0[jr]) | ((uint32_t)f2bf(a1[jr]) << 16);
        *(uint32_t*)&XT[n4 + jr][2 * cp] = pk;
      }
    }
    __syncthreads();
#pragma unroll
    for (int ks = 0; ks < 2; ++ks) {
      bf16x8 bfr[4];
#pragma unroll
      for (int nt = 0; nt < 4; ++nt)
        bfr[nt] = *(const bf16x8*)&WT[16 * nt + l15][32 * ks + 8 * g];
#pragma unroll
      for (int mt = 0; mt < 2; ++mt) {
        bf16x8 a = *(const bf16x8*)&XT[32 * wid + 16 * mt + l15][32 * ks + 8 * g];
#pragma unroll
        for (int nt = 0; nt < 4; ++nt)
          acc[mt][nt] = __builtin_amdgcn_mfma_f32_16x16x32_bf16(a, bfr[nt], acc[mt][nt], 0, 0, 0);
      }
    }
    __syncthreads();
  }
  u16* ob = oT + (size_t)b * NN * DD;
#pragma unroll
  for (int mt = 0; mt < 2; ++mt)
#pragma unroll
    for (int nt = 0; nt < 4; ++nt) {
      float bv = bias[16 * nt + l15];
#pragma unroll
      for (int r = 0; r < 4; ++r) {
        int n = n0 + 32 * wid + 16 * mt + 4 * g + r;
        ob[(size_t)n * DD + 16 * nt + l15] = f2bf(acc[mt][nt][r] + bv);
      }
    }
}

// V projection MFMA: out[b][o][n] bf16, O=512, tile 128x128
__global__ __launch_bounds__(256) void projV_mfma_kernel(
    const float* __restrict__ W, const float* __restrict__ bias,
    const float* __restrict__ X, u16* __restrict__ out)
{
  const int b = blockIdx.z;
  const int o0 = blockIdx.y * 128;
  const int n0 = blockIdx.x * 128;
  const int t = threadIdx.x;
  const int lane = t & 63, wid = t >> 6;
  const int g = lane >> 4, l15 = lane & 15;
  const int wm = (wid >> 1) * 64, wn = (wid & 1) * 64;
  __shared__ __align__(16) u16 WT[128][72];
  __shared__ __align__(16) u16 XT[128][72];
  const float* Xb = X + (size_t)b * CC * NN;
  f32x4 acc[4][4] = {};
  for (int c0 = 0; c0 < CC; c0 += 64) {
#pragma unroll
    for (int i = 0; i < 8; ++i) {   // WT: 128o x 64c
      int idx = t + 256 * i;
      int o = idx >> 4, cq = (idx & 15) * 4;
      float4 w = *(const float4*)&W[(size_t)(o0 + o) * CC + c0 + cq];
      ushort4 s; s.x = f2bf(w.x); s.y = f2bf(w.y); s.z = f2bf(w.z); s.w = f2bf(w.w);
      *(ushort4*)&WT[o][cq] = s;
    }
#pragma unroll
    for (int i = 0; i < 4; ++i) {   // XT transpose
      int idx = t + 256 * i;
      int n4 = (idx & 31) * 4, cp = idx >> 5;
      float4 v0 = *(const float4*)&Xb[(size_t)(c0 + 2 * cp) * NN + n0 + n4];
      float4 v1 = *(const float4*)&Xb[(size_t)(c0 + 2 * cp + 1) * NN + n0 + n4];
      float a0[4] = {v0.x, v0.y, v0.z, v0.w};
      float a1[4] = {v1.x, v1.y, v1.z, v1.w};
#pragma unroll
      for (int j = 0; j < 4; ++j) {
        int jr = (j + (idx & 31)) & 3;
        uint32_t pk = (uint32_t)f2bf(a0[jr]) | ((uint32_t)f2bf(a1[jr]) << 16);
        *(uint32_t*)&XT[n4 + jr][2 * cp] = pk;
      }
    }
    __syncthreads();
#pragma unroll
    for (int ks = 0; ks < 2; ++ks) {
      bf16x8 af[4], bfr[4];
#pragma unroll
      for (int mt = 0; mt < 4; ++mt)
        af[mt] = *(const bf16x8*)&WT[wm + 16 * mt + l15][32 * ks + 8 * g];
#pragma unroll
      for (int nt = 0; nt < 4; ++nt)
        bfr[nt] = *(const bf16x8*)&XT[wn + 16 * nt + l15][32 * ks + 8 * g];
#pragma unroll
      for (int mt = 0; mt < 4; ++mt)
#pragma unroll
        for (int nt = 0; nt < 4; ++nt)
          acc[mt][nt] = __builtin_amdgcn_mfma_f32_16x16x32_bf16(af[mt], bfr[nt], acc[mt][nt], 0, 0, 0);
    }
    __syncthreads();
  }
#pragma unroll
  for (int mt = 0; mt < 4; ++mt)
#pragma unroll
    for (int r = 0; r < 4; ++r) {
      int o = o0 + wm + 16 * mt + 4 * g + r;
      float bv = bias[o];
      u16* orow = out + ((size_t)b * CC + o) * NN + n0 + wn;
#pragma unroll
      for (int nt = 0; nt < 4; ++nt)
        orow[16 * nt + l15] = f2bf(acc[mt][nt][r] + bv);
    }
}

// PAM unified pass: E[q][k] = exp(S-20) (bf16), l[q] += rowsum via atomics.
// Inputs qT/kT [n][64]. Grid (q-tiles 128, k-chunks NN/KCH, NB), 256 thr.
__global__ __launch_bounds__(256) void pam_p_kernel(
    const u16* __restrict__ qT, const u16* __restrict__ kT,
    u16* __restrict__ P, float* __restrict__ lsum, int bbase)
{
  const int b = bbase + blockIdx.z;
  const int q0 = blockIdx.x * 32;
  const int kbase = blockIdx.y * KCH;
  const int t = threadIdx.x;
  const int lane = t & 63, wid = t >> 6;
  const int g = lane >> 4, l15 = lane & 15;
  __shared__ __align__(16) u16 QT[32][72];
  __shared__ __align__(16) u16 KT[128][72];
  __shared__ __align__(16) u16 ET[32][140];
  const u16* qTb = qT + (size_t)b * NN * DD;
  const u16* kTb = kT + (size_t)b * NN * DD;
  u16* Pb = P + (size_t)blockIdx.z * NN * NN;
  {
    int q = t >> 3, d8 = (t & 7) * 8;
    *(us8*)&QT[q][d8] = *(const us8*)&qTb[(size_t)(q0 + q) * DD + d8];
  }
  float ls[2][4] = {};
  for (int kk = 0; kk < KCH; kk += 128) {
#pragma unroll
    for (int i = 0; i < 4; ++i) {
      int idx = t + 256 * i;
      int k = idx >> 3, d8 = (idx & 7) * 8;
      *(us8*)&KT[k][d8] = *(const us8*)&kTb[(size_t)(kbase + kk + k) * DD + d8];
    }
    __syncthreads();
#pragma unroll
    for (int qt = 0; qt < 2; ++qt)
#pragma unroll
      for (int kt2 = 0; kt2 < 2; ++kt2) {
        f32x4 acc = {};
#pragma unroll
        for (int ks = 0; ks < 2; ++ks) {
          bf16x8 a = *(const bf16x8*)&QT[16 * qt + l15][32 * ks + 8 * g];
          bf16x8 bk = *(const bf16x8*)&KT[32 * wid + 16 * kt2 + l15][32 * ks + 8 * g];
          acc = __builtin_amdgcn_mfma_f32_16x16x32_bf16(a, bk, acc, 0, 0, 0);
        }
#pragma unroll
        for (int r = 0; r < 4; ++r) {
          float e = __expf(acc[r] - 20.f);
          ls[qt][r] += e;
          ET[16 * qt + 4 * g + r][32 * wid + 16 * kt2 + l15] = f2bf(e);
        }
      }
    __syncthreads();
#pragma unroll
    for (int i = 0; i < 2; ++i) {  // coalesced flush ET -> P
      int idx = t + 256 * i;
      int q = idx >> 4, k8 = (idx & 15) * 8;
      *(us8*)&Pb[(size_t)(q0 + q) * NN + kbase + kk + k8] = *(const us8*)&ET[q][k8];
    }
    __syncthreads();
  }
#pragma unroll
  for (int qt = 0; qt < 2; ++qt)
#pragma unroll
    for (int r = 0; r < 4; ++r) {
      float v = ls[qt][r];
      v += __shfl_xor(v, 1); v += __shfl_xor(v, 2);
      v += __shfl_xor(v, 4); v += __shfl_xor(v, 8);
      if (l15 == 0)
        atomicAdd(&lsum[(size_t)b * NN + q0 + 16 * qt + 4 * g + r], v);
    }
}

// PAM PV GEMM: out += gamma * (sum_k V[c][k] E[q][k]) / l[q] + x
__global__ __launch_bounds__(256) void pam_gemm_kernel(
    const u16* __restrict__ vp, const u16* __restrict__ P,
    const float* __restrict__ gamma, const float* __restrict__ X,
    const float* __restrict__ lsum, float* __restrict__ out, int bbase)
{
  const int b = bbase + blockIdx.z;
  const int c0 = blockIdx.y * 128;
  const int q0 = blockIdx.x * 128;
  const int t = threadIdx.x;
  const int lane = t & 63, wid = t >> 6;
  const int g = lane >> 4, l15 = lane & 15;
  const int wm = (wid >> 1) * 64, wn = (wid & 1) * 64;
  __shared__ __align__(16) u16 VT[128][88];
  __shared__ __align__(16) u16 PT[128][88];
  const u16* Vb = vp + (size_t)b * CC * NN;
  const u16* Pb = P + (size_t)blockIdx.z * NN * NN;
  f32x4 acc[4][4] = {};
  for (int k0 = 0; k0 < NN; k0 += 64) {
#pragma unroll
    for (int i = 0; i < 4; ++i) {
      int idx = t + 256 * i;
      int r = idx >> 3, k8 = (idx & 7) * 8;
      *(us8*)&VT[r][k8] = *(const us8*)&Vb[(size_t)(c0 + r) * NN + k0 + k8];
      *(us8*)&PT[r][k8] = *(const us8*)&Pb[(size_t)(q0 + r) * NN + k0 + k8];
    }
    __syncthreads();
#pragma unroll
    for (int ks = 0; ks < 2; ++ks) {
      bf16x8 af[4], bfr[4];
#pragma unroll
      for (int mt = 0; mt < 4; ++mt)
        af[mt] = *(const bf16x8*)&VT[wm + 16 * mt + l15][32 * ks + 8 * g];
#pragma unroll
      for (int nt = 0; nt < 4; ++nt)
        bfr[nt] = *(const bf16x8*)&PT[wn + 16 * nt + l15][32 * ks + 8 * g];
#pragma unroll
      for (int mt = 0; mt < 4; ++mt)
#pragma unroll
        for (int nt = 0; nt < 4; ++nt)
          acc[mt][nt] = __builtin_amdgcn_mfma_f32_16x16x32_bf16(
              af[mt], bfr[nt], acc[mt][nt], 0, 0, 0);
    }
    __syncthreads();
  }
  const float gv = gamma[0];
  float rl[4];
#pragma unroll
  for (int nt = 0; nt < 4; ++nt)
    rl[nt] = 1.f / lsum[(size_t)b * NN + q0 + wn + 16 * nt + l15];
#pragma unroll
  for (int mt = 0; mt < 4; ++mt) {
    int c = c0 + wm + 16 * mt + 4 * g;
#pragma unroll
    for (int r = 0; r < 4; ++r) {
      size_t rowoff = ((size_t)b * CC + c + r) * NN;
#pragma unroll
      for (int nt = 0; nt < 4; ++nt) {
        size_t off = rowoff + q0 + wn + 16 * nt + l15;
        out[off] += gv * acc[mt][nt][r] * rl[nt] + X[off];
      }
    }
  }
}

// CAM energy (SIMT)
__global__ __launch_bounds__(256) void cam_energy_kernel(
    const u16* __restrict__ qc, const u16* __restrict__ kc, float* __restrict__ eC)
{
  const int b = blockIdx.z;
  const int i0 = blockIdx.y << 6;
  const int j0 = blockIdx.x << 6;
  const int t = threadIdx.x;
  const int tx = t & 15, ty = t >> 4;
  __shared__ float At[32][68];
  __shared__ float Bt[32][68];
  const u16* qb = qc + (size_t)b * CC * CC;
  const u16* kb = kc + (size_t)b * CC * CC;
  float o[4][4];
#pragma unroll
  for (int i = 0; i < 4; ++i)
#pragma unroll
    for (int j = 0; j < 4; ++j) o[i][j] = 0.f;
  for (int m0 = 0; m0 < CC; m0 += 32) {
#pragma unroll
    for (int i = 0; i < 8; ++i) {
      int lin = t + (i << 8);
      int ci = lin >> 5, m = lin & 31;
      At[m][ci] = bf2f(qb[(i0 + ci) * CC + m0 + m]);
      Bt[m][ci] = bf2f(kb[(j0 + ci) * CC + m0 + m]);
    }
    __syncthreads();
#pragma unroll
    for (int m = 0; m < 32; ++m) {
      float4 a = *(const float4*)&At[m][ty * 4];
      float4 bv = *(const float4*)&Bt[m][tx * 4];
      o[0][0] += a.x * bv.x; o[0][1] += a.x * bv.y; o[0][2] += a.x * bv.z; o[0][3] += a.x * bv.w;
      o[1][0] += a.y * bv.x; o[1][1] += a.y * bv.y; o[1][2] += a.y * bv.z; o[1][3] += a.y * bv.w;
      o[2][0] += a.z * bv.x; o[2][1] += a.z * bv.y; o[2][2] += a.z * bv.z; o[2][3] += a.z * bv.w;
      o[3][0] += a.w * bv.x; o[3][1] += a.w * bv.y; o[3][2] += a.w * bv.z; o[3][3] += a.w * bv.w;
    }
    __syncthreads();
  }
  float* eb = eC + (size_t)b * CC * CC;
#pragma unroll
  for (int i = 0; i < 4; ++i) {
    float4 v;
    v.x = o[i][0]; v.y = o[i][1]; v.z = o[i][2]; v.w = o[i][3];
    *(float4*)&eb[(i0 + ty * 4 + i) * CC + j0 + tx * 4] = v;
  }
}

__global__ __launch_bounds__(256) void cam_softmax_kernel(float* __restrict__ eC)
{
  const int b = blockIdx.y, ci = blockIdx.x;
  float* row = eC + ((size_t)b * CC + ci) * CC;
  const int t = threadIdx.x;
  float e0 = row[t], e1 = row[t + 256];
  __shared__ float red[256];
  red[t] = fminf(e0, e1);
  __syncthreads();
  for (int w = 128; w > 0; w >>= 1) {
    if (t < w) red[t] = fminf(red[t], red[t + w]);
    __syncthreads();
  }
  float rmin = red[0];
  __syncthreads();
  float p0 = __expf(rmin - e0), p1 = __expf(rmin - e1);
  red[t] = p0 + p1;
  __syncthreads();
  for (int w = 128; w > 0; w >>= 1) {
    if (t < w) red[t] += red[t + w];
    __syncthreads();
  }
  float inv = 1.f / red[0];
  row[t] = p0 * inv;
  row[t + 256] = p1 * inv;
}

// CAM PV partial (SIMT): out(f32) = gamma_c * attn@V + x
__global__ __launch_bounds__(256) void cam_pv_partial_kernel(
    const float* __restrict__ attn, const u16* __restrict__ vc,
    const float* __restrict__ gamma, const float* __restrict__ X,
    float* __restrict__ outp)
{
  const int b = blockIdx.z;
  const int c00 = blockIdx.y << 6;
  const int n0 = blockIdx.x << 6;
  const int t = threadIdx.x;
  const int tx = t & 15, ty = t >> 4;
  __shared__ float At[32][68];
  __shared__ float Bt[32][64];
  const float* Ab = attn + (size_t)b * CC * CC;
  const u16* Vb = vc + (size_t)b * CC * NN;
  float o[4][4];
#pragma unroll
  for (int i = 0; i < 4; ++i)
#pragma unroll
    for (int j = 0; j < 4; ++j) o[i][j] = 0.f;
  for (int d0 = 0; d0 < CC; d0 += 32) {
#pragma unroll
    for (int i = 0; i < 8; ++i) {
      int lin = t + (i << 8);
      int c = lin >> 5, d = lin & 31;
      At[d][c] = Ab[(c00 + c) * CC + d0 + d];
    }
#pragma unroll
    for (int i = 0; i < 8; ++i) {
      int lin = t + (i << 8);
      int d = lin >> 6, n = lin & 63;
      Bt[d][n] = bf2f(Vb[(d0 + d) * NN + n0 + n]);
    }
    __syncthreads();
#pragma unroll
    for (int d = 0; d < 32; ++d) {
      float4 a = *(const float4*)&At[d][ty * 4];
      float4 bv = *(const float4*)&Bt[d][tx * 4];
      o[0][0] += a.x * bv.x; o[0][1] += a.x * bv.y; o[0][2] += a.x * bv.z; o[0][3] += a.x * bv.w;
      o[1][0] += a.y * bv.x; o[1][1] += a.y * bv.y; o[1][2] += a.y * bv.z; o[1][3] += a.y * bv.w;
      o[2][0] += a.z * bv.x; o[2][1] += a.z * bv.y; o[2][2] += a.z * bv.z; o[2][3] += a.z * bv.w;
      o[3][0] += a.w * bv.x; o[3][1] += a.w * bv.y; o[3][2] += a.w * bv.z; o[3][3] += a.w * bv.w;
    }
    __syncthreads();
  }
  float g = gamma[0];
  const float* xpb = X + ((size_t)b * CC + c00) * NN;
  float* opb = outp + ((size_t)b * CC + c00) * NN;
#pragma unroll
  for (int i = 0; i < 4; ++i) {
    size_t off = (size_t)(ty * 4 + i) * NN + n0 + tx * 4;
    float4 xv = *(const float4*)&xpb[off];
    float4 r;
    r.x = g * o[i][0] + xv.x;
    r.y = g * o[i][1] + xv.y;
    r.z = g * o[i][2] + xv.z;
    r.w = g * o[i][3] + xv.w;
    *(float4*)&opb[off] = r;
  }
}

extern "C" void kernel_launch(void* const* d_in, const int* in_sizes, int n_in,
                              void* d_out, int out_size, void* d_ws, size_t ws_size,
                              hipStream_t stream) {
  const float* x   = (const float*)d_in[0];
  const float* pwq = (const float*)d_in[1];
  const float* pbq = (const float*)d_in[2];
  const float* pwk = (const float*)d_in[3];
  const float* pbk = (const float*)d_in[4];
  const float* pwv = (const float*)d_in[5];
  const float* pbv = (const float*)d_in[6];
  const float* pgam= (const float*)d_in[7];
  const float* cwq = (const float*)d_in[8];
  const float* cbq = (const float*)d_in[9];
  const float* cwk = (const float*)d_in[10];
  const float* cbk = (const float*)d_in[11];
  const float* cwv = (const float*)d_in[12];
  const float* cbv = (const float*)d_in[13];
  const float* cgam= (const float*)d_in[14];
  float* out = (float*)d_out;

  const size_t SMALL = (size_t)BB * DD * NN;
  const size_t BIG   = (size_t)BB * CC * NN;
  u16* vbuf = (u16*)d_ws;
  u16* qbuf = vbuf + BIG;
  u16* kbuf = qbuf + SMALL;
  float* eC = (float*)(kbuf + SMALL);
  float* lsum = eC + (size_t)BB * CC * CC;
  u16* Pws = (u16*)(lsum + (size_t)BB * NN);
  size_t fixed = (size_t)((char*)Pws - (char*)d_ws);
  int NB = 1;
  if (ws_size >= fixed + 4ull * NN * NN * 2) NB = 4;
  else if (ws_size >= fixed + 2ull * NN * NN * 2) NB = 2;

  dim3 blk(256);
  // ---- CAM phase: d_out <- gamma_c*outC + x ----
  proj_kernel<<<dim3(64, 1, BB), blk, 0, stream>>>(cwq, cbq, x, qbuf, DD);
  proj_kernel<<<dim3(64, 1, BB), blk, 0, stream>>>(cwk, cbk, x, kbuf, DD);
  projV_mfma_kernel<<<dim3(32, 4, BB), blk, 0, stream>>>(cwv, cbv, x, vbuf);
  cam_energy_kernel<<<dim3(8, 8, BB), blk, 0, stream>>>(qbuf, kbuf, eC);
  cam_softmax_kernel<<<dim3(CC, BB), blk, 0, stream>>>(eC);
  cam_pv_partial_kernel<<<dim3(64, 8, BB), blk, 0, stream>>>(eC, vbuf, cgam, x, out);
  // ---- PAM phase: d_out += gamma_p*outP + x ----
  projT_mfma_kernel<<<dim3(32, 1, BB), blk, 0, stream>>>(pwq, pbq, x, qbuf);
  projT_mfma_kernel<<<dim3(32, 1, BB), blk, 0, stream>>>(pwk, pbk, x, kbuf);
  projV_mfma_kernel<<<dim3(32, 4, BB), blk, 0, stream>>>(pwv, pbv, x, vbuf);
  zero_kernel<<<dim3((BB * NN) / 256), blk, 0, stream>>>(lsum, BB * NN);
  for (int bb = 0; bb < BB; bb += NB) {
    pam_p_kernel<<<dim3(NN / 32, NN / KCH, NB), blk, 0, stream>>>(qbuf, kbuf, Pws, lsum, bb);
    pam_gemm_kernel<<<dim3(NN / 128, CC / 128, NB), blk, 0, stream>>>(
        vbuf, Pws, pgam, x, lsum, out, bb);
  }
}

// Round 10
// 490.220 us; speedup vs baseline: 5.9342x; 1.2309x over previous
//
#include <hip/hip_runtime.h>
#include <cstdint>

#define BB 4
#define CC 512
#define DD 64
#define NN 4096
#define KCH 512

typedef unsigned short u16;
typedef __attribute__((ext_vector_type(8))) short bf16x8;
typedef __attribute__((ext_vector_type(4))) float f32x4;
typedef __attribute__((ext_vector_type(8))) unsigned short us8;

__device__ __forceinline__ float bf2f(u16 u) {
  union { unsigned int i; float f; } v; v.i = ((unsigned int)u) << 16; return v.f;
}
__device__ __forceinline__ u16 f2bf(float f) {
  unsigned int x = __float_as_uint(f);
  if ((x & 0x7fffffffu) > 0x7f800000u) return (u16)0x7fc0;
  return (u16)((x + 0x7fffu + ((x >> 16) & 1u)) >> 16);
}

__global__ __launch_bounds__(256) void zero_kernel(float* __restrict__ p, int n) {
  int i = blockIdx.x * 256 + threadIdx.x;
  if (i < n) p[i] = 0.f;
}

// PAM q/k projection, MFMA, TRANSPOSED output: oT[b][n][64]
__global__ __launch_bounds__(256) void projT_mfma_kernel(
    const float* __restrict__ W, const float* __restrict__ bias,
    const float* __restrict__ X, u16* __restrict__ oT)
{
  const int b = blockIdx.z;
  const int n0 = blockIdx.x * 128;
  const int t = threadIdx.x;
  const int lane = t & 63, wid = t >> 6;
  const int g = lane >> 4, l15 = lane & 15;
  __shared__ __align__(16) u16 XT[128][72];  // [n][c-slice]
  __shared__ __align__(16) u16 WT[64][72];   // [o][c-slice]
  const float* Xb = X + (size_t)b * CC * NN;
  f32x4 acc[2][4] = {};
  for (int c0 = 0; c0 < CC; c0 += 64) {
#pragma unroll
    for (int i = 0; i < 4; ++i) {   // WT: 64o x 64c
      int idx = t + 256 * i;
      int o = idx >> 4, cq = (idx & 15) * 4;
      float4 w = *(const float4*)&W[(size_t)o * CC + c0 + cq];
      ushort4 s; s.x = f2bf(w.x); s.y = f2bf(w.y); s.z = f2bf(w.z); s.w = f2bf(w.w);
      *(ushort4*)&WT[o][cq] = s;
    }
#pragma unroll
    for (int i = 0; i < 4; ++i) {   // XT: 128n x 64c pack-pair transpose
      int idx = t + 256 * i;
      int n4 = (idx & 31) * 4, cp = idx >> 5;
      float4 v0 = *(const float4*)&Xb[(size_t)(c0 + 2 * cp) * NN + n0 + n4];
      float4 v1 = *(const float4*)&Xb[(size_t)(c0 + 2 * cp + 1) * NN + n0 + n4];
      float a0[4] = {v0.x, v0.y, v0.z, v0.w};
      float a1[4] = {v1.x, v1.y, v1.z, v1.w};
#pragma unroll
      for (int j = 0; j < 4; ++j) {
        int jr = (j + (idx & 31)) & 3;  // lane-rotated to spread LDS banks
        uint32_t pk = (uint32_t)f2bf(a0[jr]) | ((uint32_t)f2bf(a1[jr]) << 16);
        *(uint32_t*)&XT[n4 + jr][2 * cp] = pk;
      }
    }
    __syncthreads();
#pragma unroll
    for (int ks = 0; ks < 2; ++ks) {
      bf16x8 bfr[4];
#pragma unroll
      for (int nt = 0; nt < 4; ++nt)
        bfr[nt] = *(const bf16x8*)&WT[16 * nt + l15][32 * ks + 8 * g];
#pragma unroll
      for (int mt = 0; mt < 2; ++mt) {
        bf16x8 a = *(const bf16x8*)&XT[32 * wid + 16 * mt + l15][32 * ks + 8 * g];
#pragma unroll
        for (int nt = 0; nt < 4; ++nt)
          acc[mt][nt] = __builtin_amdgcn_mfma_f32_16x16x32_bf16(a, bfr[nt], acc[mt][nt], 0, 0, 0);
      }
    }
    __syncthreads();
  }
  u16* ob = oT + (size_t)b * NN * DD;
#pragma unroll
  for (int mt = 0; mt < 2; ++mt)
#pragma unroll
    for (int nt = 0; nt < 4; ++nt) {
      float bv = bias[16 * nt + l15];
#pragma unroll
      for (int r = 0; r < 4; ++r) {
        int n = n0 + 32 * wid + 16 * mt + 4 * g + r;
        ob[(size_t)n * DD + 16 * nt + l15] = f2bf(acc[mt][nt][r] + bv);
      }
    }
}

// V projection MFMA: out[b][o][n] bf16, O=512, tile 128x128
__global__ __launch_bounds__(256) void projV_mfma_kernel(
    const float* __restrict__ W, const float* __restrict__ bias,
    const float* __restrict__ X, u16* __restrict__ out)
{
  const int b = blockIdx.z;
  const int o0 = blockIdx.y * 128;
  const int n0 = blockIdx.x * 128;
  const int t = threadIdx.x;
  const int lane = t & 63, wid = t >> 6;
  const int g = lane >> 4, l15 = lane & 15;
  const int wm = (wid >> 1) * 64, wn = (wid & 1) * 64;
  __shared__ __align__(16) u16 WT[128][72];
  __shared__ __align__(16) u16 XT[128][72];
  const float* Xb = X + (size_t)b * CC * NN;
  f32x4 acc[4][4] = {};
  for (int c0 = 0; c0 < CC; c0 += 64) {
#pragma unroll
    for (int i = 0; i < 8; ++i) {   // WT: 128o x 64c
      int idx = t + 256 * i;
      int o = idx >> 4, cq = (idx & 15) * 4;
      float4 w = *(const float4*)&W[(size_t)(o0 + o) * CC + c0 + cq];
      ushort4 s; s.x = f2bf(w.x); s.y = f2bf(w.y); s.z = f2bf(w.z); s.w = f2bf(w.w);
      *(ushort4*)&WT[o][cq] = s;
    }
#pragma unroll
    for (int i = 0; i < 4; ++i) {   // XT transpose
      int idx = t + 256 * i;
      int n4 = (idx & 31) * 4, cp = idx >> 5;
      float4 v0 = *(const float4*)&Xb[(size_t)(c0 + 2 * cp) * NN + n0 + n4];
      float4 v1 = *(const float4*)&Xb[(size_t)(c0 + 2 * cp + 1) * NN + n0 + n4];
      float a0[4] = {v0.x, v0.y, v0.z, v0.w};
      float a1[4] = {v1.x, v1.y, v1.z, v1.w};
#pragma unroll
      for (int j = 0; j < 4; ++j) {
        int jr = (j + (idx & 31)) & 3;
        uint32_t pk = (uint32_t)f2bf(a0[jr]) | ((uint32_t)f2bf(a1[jr]) << 16);
        *(uint32_t*)&XT[n4 + jr][2 * cp] = pk;
      }
    }
    __syncthreads();
#pragma unroll
    for (int ks = 0; ks < 2; ++ks) {
      bf16x8 af[4], bfr[4];
#pragma unroll
      for (int mt = 0; mt < 4; ++mt)
        af[mt] = *(const bf16x8*)&WT[wm + 16 * mt + l15][32 * ks + 8 * g];
#pragma unroll
      for (int nt = 0; nt < 4; ++nt)
        bfr[nt] = *(const bf16x8*)&XT[wn + 16 * nt + l15][32 * ks + 8 * g];
#pragma unroll
      for (int mt = 0; mt < 4; ++mt)
#pragma unroll
        for (int nt = 0; nt < 4; ++nt)
          acc[mt][nt] = __builtin_amdgcn_mfma_f32_16x16x32_bf16(af[mt], bfr[nt], acc[mt][nt], 0, 0, 0);
    }
    __syncthreads();
  }
#pragma unroll
  for (int mt = 0; mt < 4; ++mt)
#pragma unroll
    for (int r = 0; r < 4; ++r) {
      int o = o0 + wm + 16 * mt + 4 * g + r;
      float bv = bias[o];
      u16* orow = out + ((size_t)b * CC + o) * NN + n0 + wn;
#pragma unroll
      for (int nt = 0; nt < 4; ++nt)
        orow[16 * nt + l15] = f2bf(acc[mt][nt][r] + bv);
    }
}

// V projection MFMA, TRANSPOSED: vT[b][n][o], O=512, tile 128n x 128o
__global__ __launch_bounds__(256) void projVT_mfma_kernel(
    const float* __restrict__ W, const float* __restrict__ bias,
    const float* __restrict__ X, u16* __restrict__ vT)
{
  const int b = blockIdx.z;
  const int o0 = blockIdx.y * 128;
  const int n0 = blockIdx.x * 128;
  const int t = threadIdx.x;
  const int lane = t & 63, wid = t >> 6;
  const int g = lane >> 4, l15 = lane & 15;
  const int wm = (wid >> 1) * 64, wn = (wid & 1) * 64;
  __shared__ __align__(16) u16 WT[128][72];
  __shared__ __align__(16) u16 XT[128][72];
  const float* Xb = X + (size_t)b * CC * NN;
  f32x4 acc[4][4] = {};
  for (int c0 = 0; c0 < CC; c0 += 64) {
#pragma unroll
    for (int i = 0; i < 8; ++i) {
      int idx = t + 256 * i;
      int o = idx >> 4, cq = (idx & 15) * 4;
      float4 w = *(const float4*)&W[(size_t)(o0 + o) * CC + c0 + cq];
      ushort4 s; s.x = f2bf(w.x); s.y = f2bf(w.y); s.z = f2bf(w.z); s.w = f2bf(w.w);
      *(ushort4*)&WT[o][cq] = s;
    }
#pragma unroll
    for (int i = 0; i < 4; ++i) {
      int idx = t + 256 * i;
      int n4 = (idx & 31) * 4, cp = idx >> 5;
      float4 v0 = *(const float4*)&Xb[(size_t)(c0 + 2 * cp) * NN + n0 + n4];
      float4 v1 = *(const float4*)&Xb[(size_t)(c0 + 2 * cp + 1) * NN + n0 + n4];
      float a0[4] = {v0.x, v0.y, v0.z, v0.w};
      float a1[4] = {v1.x, v1.y, v1.z, v1.w};
#pragma unroll
      for (int j = 0; j < 4; ++j) {
        int jr = (j + (idx & 31)) & 3;
        uint32_t pk = (uint32_t)f2bf(a0[jr]) | ((uint32_t)f2bf(a1[jr]) << 16);
        *(uint32_t*)&XT[n4 + jr][2 * cp] = pk;
      }
    }
    __syncthreads();
#pragma unroll
    for (int ks = 0; ks < 2; ++ks) {
      bf16x8 af[4], bfr[4];
#pragma unroll
      for (int mt = 0; mt < 4; ++mt)     // m-dim = n rows
        af[mt] = *(const bf16x8*)&XT[wm + 16 * mt + l15][32 * ks + 8 * g];
#pragma unroll
      for (int nt = 0; nt < 4; ++nt)     // col = o rows
        bfr[nt] = *(const bf16x8*)&WT[wn + 16 * nt + l15][32 * ks + 8 * g];
#pragma unroll
      for (int mt = 0; mt < 4; ++mt)
#pragma unroll
        for (int nt = 0; nt < 4; ++nt)
          acc[mt][nt] = __builtin_amdgcn_mfma_f32_16x16x32_bf16(af[mt], bfr[nt], acc[mt][nt], 0, 0, 0);
    }
    __syncthreads();
  }
  u16* vb = vT + (size_t)b * NN * CC;
#pragma unroll
  for (int mt = 0; mt < 4; ++mt)
#pragma unroll
    for (int r = 0; r < 4; ++r) {
      int n = n0 + wm + 16 * mt + 4 * g + r;
      u16* nrow = vb + (size_t)n * CC + o0 + wn;
#pragma unroll
      for (int nt = 0; nt < 4; ++nt)
        nrow[16 * nt + l15] = f2bf(acc[mt][nt][r] + bias[o0 + wn + 16 * nt + l15]);
    }
}

// CAM q/k projection MFMA: out[b][o][n], O=64, tile 64o x 128n
__global__ __launch_bounds__(256) void proj64_mfma_kernel(
    const float* __restrict__ W, const float* __restrict__ bias,
    const float* __restrict__ X, u16* __restrict__ out)
{
  const int b = blockIdx.z;
  const int n0 = blockIdx.x * 128;
  const int t = threadIdx.x;
  const int lane = t & 63, wid = t >> 6;
  const int g = lane >> 4, l15 = lane & 15;
  const int wm = (wid >> 1) * 32, wn = (wid & 1) * 64;
  __shared__ __align__(16) u16 WT[64][72];
  __shared__ __align__(16) u16 XT[128][72];
  const float* Xb = X + (size_t)b * CC * NN;
  f32x4 acc[2][4] = {};
  for (int c0 = 0; c0 < CC; c0 += 64) {
#pragma unroll
    for (int i = 0; i < 4; ++i) {
      int idx = t + 256 * i;
      int o = idx >> 4, cq = (idx & 15) * 4;
      float4 w = *(const float4*)&W[(size_t)o * CC + c0 + cq];
      ushort4 s; s.x = f2bf(w.x); s.y = f2bf(w.y); s.z = f2bf(w.z); s.w = f2bf(w.w);
      *(ushort4*)&WT[o][cq] = s;
    }
#pragma unroll
    for (int i = 0; i < 4; ++i) {
      int idx = t + 256 * i;
      int n4 = (idx & 31) * 4, cp = idx >> 5;
      float4 v0 = *(const float4*)&Xb[(size_t)(c0 + 2 * cp) * NN + n0 + n4];
      float4 v1 = *(const float4*)&Xb[(size_t)(c0 + 2 * cp + 1) * NN + n0 + n4];
      float a0[4] = {v0.x, v0.y, v0.z, v0.w};
      float a1[4] = {v1.x, v1.y, v1.z, v1.w};
#pragma unroll
      for (int j = 0; j < 4; ++j) {
        int jr = (j + (idx & 31)) & 3;
        uint32_t pk = (uint32_t)f2bf(a0[jr]) | ((uint32_t)f2bf(a1[jr]) << 16);
        *(uint32_t*)&XT[n4 + jr][2 * cp] = pk;
      }
    }
    __syncthreads();
#pragma unroll
    for (int ks = 0; ks < 2; ++ks) {
      bf16x8 bfr[4];
#pragma unroll
      for (int nt = 0; nt < 4; ++nt)
        bfr[nt] = *(const bf16x8*)&XT[wn + 16 * nt + l15][32 * ks + 8 * g];
#pragma unroll
      for (int mt = 0; mt < 2; ++mt) {
        bf16x8 a = *(const bf16x8*)&WT[wm + 16 * mt + l15][32 * ks + 8 * g];
#pragma unroll
        for (int nt = 0; nt < 4; ++nt)
          acc[mt][nt] = __builtin_amdgcn_mfma_f32_16x16x32_bf16(a, bfr[nt], acc[mt][nt], 0, 0, 0);
      }
    }
    __syncthreads();
  }
  u16* ob = out + (size_t)b * DD * NN;
#pragma unroll
  for (int mt = 0; mt < 2; ++mt)
#pragma unroll
    for (int r = 0; r < 4; ++r) {
      int o = wm + 16 * mt + 4 * g + r;
      float bv = bias[o];
      u16* orow = ob + (size_t)o * NN + n0 + wn;
#pragma unroll
      for (int nt = 0; nt < 4; ++nt)
        orow[16 * nt + l15] = f2bf(acc[mt][nt][r] + bv);
    }
}

// CAM energy MFMA: e[ci][cj] = sum_m q[ci][m] k[cj][m], q/k = [512][512] bf16
__global__ __launch_bounds__(256) void cam_energy_mfma_kernel(
    const u16* __restrict__ qc, const u16* __restrict__ kc, float* __restrict__ eC)
{
  const int b = blockIdx.z;
  const int i0 = blockIdx.y * 128;
  const int j0 = blockIdx.x * 128;
  const int t = threadIdx.x;
  const int lane = t & 63, wid = t >> 6;
  const int g = lane >> 4, l15 = lane & 15;
  const int wm = (wid >> 1) * 64, wn = (wid & 1) * 64;
  __shared__ __align__(16) u16 QT[128][72];
  __shared__ __align__(16) u16 KT[128][72];
  const u16* qb = qc + (size_t)b * CC * CC;
  const u16* kb = kc + (size_t)b * CC * CC;
  f32x4 acc[4][4] = {};
  for (int m0 = 0; m0 < CC; m0 += 64) {
#pragma unroll
    for (int i = 0; i < 4; ++i) {
      int idx = t + 256 * i;
      int r = idx >> 3, k8 = (idx & 7) * 8;
      *(us8*)&QT[r][k8] = *(const us8*)&qb[(size_t)(i0 + r) * CC + m0 + k8];
      *(us8*)&KT[r][k8] = *(const us8*)&kb[(size_t)(j0 + r) * CC + m0 + k8];
    }
    __syncthreads();
#pragma unroll
    for (int ks = 0; ks < 2; ++ks) {
      bf16x8 af[4], bfr[4];
#pragma unroll
      for (int mt = 0; mt < 4; ++mt)
        af[mt] = *(const bf16x8*)&QT[wm + 16 * mt + l15][32 * ks + 8 * g];
#pragma unroll
      for (int nt = 0; nt < 4; ++nt)
        bfr[nt] = *(const bf16x8*)&KT[wn + 16 * nt + l15][32 * ks + 8 * g];
#pragma unroll
      for (int mt = 0; mt < 4; ++mt)
#pragma unroll
        for (int nt = 0; nt < 4; ++nt)
          acc[mt][nt] = __builtin_amdgcn_mfma_f32_16x16x32_bf16(af[mt], bfr[nt], acc[mt][nt], 0, 0, 0);
    }
    __syncthreads();
  }
  float* eb = eC + (size_t)b * CC * CC;
#pragma unroll
  for (int mt = 0; mt < 4; ++mt)
#pragma unroll
    for (int r = 0; r < 4; ++r) {
      int ci = i0 + wm + 16 * mt + 4 * g + r;
      float* erow = eb + (size_t)ci * CC + j0 + wn;
#pragma unroll
      for (int nt = 0; nt < 4; ++nt)
        erow[16 * nt + l15] = acc[mt][nt][r];
    }
}

// CAM softmax of (rowmax - e) == exp(rowmin - e)/sum -> bf16 attn
__global__ __launch_bounds__(256) void cam_softmax_kernel(
    const float* __restrict__ eC, u16* __restrict__ attnB)
{
  const int b = blockIdx.y, ci = blockIdx.x;
  const float* row = eC + ((size_t)b * CC + ci) * CC;
  u16* arow = attnB + ((size_t)b * CC + ci) * CC;
  const int t = threadIdx.x;
  float e0 = row[t], e1 = row[t + 256];
  __shared__ float red[256];
  red[t] = fminf(e0, e1);
  __syncthreads();
  for (int w = 128; w > 0; w >>= 1) {
    if (t < w) red[t] = fminf(red[t], red[t + w]);
    __syncthreads();
  }
  float rmin = red[0];
  __syncthreads();
  float p0 = __expf(rmin - e0), p1 = __expf(rmin - e1);
  red[t] = p0 + p1;
  __syncthreads();
  for (int w = 128; w > 0; w >>= 1) {
    if (t < w) red[t] += red[t + w];
    __syncthreads();
  }
  float inv = 1.f / red[0];
  arow[t] = f2bf(p0 * inv);
  arow[t + 256] = f2bf(p1 * inv);
}

// CAM PV MFMA: out[c][n] = gamma_c * sum_d attn[c][d] vT[n][d] + x
__global__ __launch_bounds__(256) void cam_gemm_kernel(
    const u16* __restrict__ attnB, const u16* __restrict__ vT,
    const float* __restrict__ gamma, const float* __restrict__ X,
    float* __restrict__ out)
{
  const int b = blockIdx.z;
  const int c0 = blockIdx.y * 128;
  const int n0 = blockIdx.x * 128;
  const int t = threadIdx.x;
  const int lane = t & 63, wid = t >> 6;
  const int g = lane >> 4, l15 = lane & 15;
  const int wm = (wid >> 1) * 64, wn = (wid & 1) * 64;
  __shared__ __align__(16) u16 AT[128][72];
  __shared__ __align__(16) u16 VTl[128][72];
  const u16* Ab = attnB + (size_t)b * CC * CC;
  const u16* Vb = vT + (size_t)b * NN * CC;
  f32x4 acc[4][4] = {};
  for (int d0 = 0; d0 < CC; d0 += 64) {
#pragma unroll
    for (int i = 0; i < 4; ++i) {
      int idx = t + 256 * i;
      int r = idx >> 3, k8 = (idx & 7) * 8;
      *(us8*)&AT[r][k8]  = *(const us8*)&Ab[(size_t)(c0 + r) * CC + d0 + k8];
      *(us8*)&VTl[r][k8] = *(const us8*)&Vb[(size_t)(n0 + r) * CC + d0 + k8];
    }
    __syncthreads();
#pragma unroll
    for (int ks = 0; ks < 2; ++ks) {
      bf16x8 af[4], bfr[4];
#pragma unroll
      for (int mt = 0; mt < 4; ++mt)
        af[mt] = *(const bf16x8*)&AT[wm + 16 * mt + l15][32 * ks + 8 * g];
#pragma unroll
      for (int nt = 0; nt < 4; ++nt)
        bfr[nt] = *(const bf16x8*)&VTl[wn + 16 * nt + l15][32 * ks + 8 * g];
#pragma unroll
      for (int mt = 0; mt < 4; ++mt)
#pragma unroll
        for (int nt = 0; nt < 4; ++nt)
          acc[mt][nt] = __builtin_amdgcn_mfma_f32_16x16x32_bf16(af[mt], bfr[nt], acc[mt][nt], 0, 0, 0);
    }
    __syncthreads();
  }
  const float gv = gamma[0];
#pragma unroll
  for (int mt = 0; mt < 4; ++mt) {
#pragma unroll
    for (int r = 0; r < 4; ++r) {
      int c = c0 + wm + 16 * mt + 4 * g + r;
      size_t rowoff = ((size_t)b * CC + c) * NN;
#pragma unroll
      for (int nt = 0; nt < 4; ++nt) {
        size_t off = rowoff + n0 + wn + 16 * nt + l15;
        out[off] = gv * acc[mt][nt][r] + X[off];
      }
    }
  }
}

// PAM unified pass: E[q][k] = exp(S-20) (bf16), l[q] += rowsum via atomics.
__global__ __launch_bounds__(256) void pam_p_kernel(
    const u16* __restrict__ qT, const u16* __restrict__ kT,
    u16* __restrict__ P, float* __restrict__ lsum, int bbase)
{
  const int b = bbase + blockIdx.z;
  const int q0 = blockIdx.x * 32;
  const int kbase = blockIdx.y * KCH;
  const int t = threadIdx.x;
  const int lane = t & 63, wid = t >> 6;
  const int g = lane >> 4, l15 = lane & 15;
  __shared__ __align__(16) u16 QT[32][72];
  __shared__ __align__(16) u16 KT[128][72];
  __shared__ __align__(16) u16 ET[32][140];
  const u16* qTb = qT + (size_t)b * NN * DD;
  const u16* kTb = kT + (size_t)b * NN * DD;
  u16* Pb = P + (size_t)blockIdx.z * NN * NN;
  {
    int q = t >> 3, d8 = (t & 7) * 8;
    *(us8*)&QT[q][d8] = *(const us8*)&qTb[(size_t)(q0 + q) * DD + d8];
  }
  float ls[2][4] = {};
  for (int kk = 0; kk < KCH; kk += 128) {
#pragma unroll
    for (int i = 0; i < 4; ++i) {
      int idx = t + 256 * i;
      int k = idx >> 3, d8 = (idx & 7) * 8;
      *(us8*)&KT[k][d8] = *(const us8*)&kTb[(size_t)(kbase + kk + k) * DD + d8];
    }
    __syncthreads();
#pragma unroll
    for (int qt = 0; qt < 2; ++qt)
#pragma unroll
      for (int kt2 = 0; kt2 < 2; ++kt2) {
        f32x4 acc = {};
#pragma unroll
        for (int ks = 0; ks < 2; ++ks) {
          bf16x8 a = *(const bf16x8*)&QT[16 * qt + l15][32 * ks + 8 * g];
          bf16x8 bk = *(const bf16x8*)&KT[32 * wid + 16 * kt2 + l15][32 * ks + 8 * g];
          acc = __builtin_amdgcn_mfma_f32_16x16x32_bf16(a, bk, acc, 0, 0, 0);
        }
#pragma unroll
        for (int r = 0; r < 4; ++r) {
          float e = __expf(acc[r] - 20.f);
          ls[qt][r] += e;
          ET[16 * qt + 4 * g + r][32 * wid + 16 * kt2 + l15] = f2bf(e);
        }
      }
    __syncthreads();
#pragma unroll
    for (int i = 0; i < 2; ++i) {  // coalesced flush ET -> P
      int idx = t + 256 * i;
      int q = idx >> 4, k8 = (idx & 15) * 8;
      *(us8*)&Pb[(size_t)(q0 + q) * NN + kbase + kk + k8] = *(const us8*)&ET[q][k8];
    }
    __syncthreads();
  }
#pragma unroll
  for (int qt = 0; qt < 2; ++qt)
#pragma unroll
    for (int r = 0; r < 4; ++r) {
      float v = ls[qt][r];
      v += __shfl_xor(v, 1); v += __shfl_xor(v, 2);
      v += __shfl_xor(v, 4); v += __shfl_xor(v, 8);
      if (l15 == 0)
        atomicAdd(&lsum[(size_t)b * NN + q0 + 16 * qt + 4 * g + r], v);
    }
}

// PAM PV GEMM: out += gamma * (sum_k V[c][k] E[q][k]) / l[q] + x
__global__ __launch_bounds__(256) void pam_gemm_kernel(
    const u16* __restrict__ vp, const u16* __restrict__ P,
    const float* __restrict__ gamma, const float* __restrict__ X,
    const float* __restrict__ lsum, float* __restrict__ out, int bbase)
{
  const int b = bbase + blockIdx.z;
  const int c0 = blockIdx.y * 128;
  const int q0 = blockIdx.x * 128;
  const int t = threadIdx.x;
  const int lane = t & 63, wid = t >> 6;
  const int g = lane >> 4, l15 = lane & 15;
  const int wm = (wid >> 1) * 64, wn = (wid & 1) * 64;
  __shared__ __align__(16) u16 VT[128][88];
  __shared__ __align__(16) u16 PT[128][88];
  const u16* Vb = vp + (size_t)b * CC * NN;
  const u16* Pb = P + (size_t)blockIdx.z * NN * NN;
  f32x4 acc[4][4] = {};
  for (int k0 = 0; k0 < NN; k0 += 64) {
#pragma unroll
    for (int i = 0; i < 4; ++i) {
      int idx = t + 256 * i;
      int r = idx >> 3, k8 = (idx & 7) * 8;
      *(us8*)&VT[r][k8] = *(const us8*)&Vb[(size_t)(c0 + r) * NN + k0 + k8];
      *(us8*)&PT[r][k8] = *(const us8*)&Pb[(size_t)(q0 + r) * NN + k0 + k8];
    }
    __syncthreads();
#pragma unroll
    for (int ks = 0; ks < 2; ++ks) {
      bf16x8 af[4], bfr[4];
#pragma unroll
      for (int mt = 0; mt < 4; ++mt)
        af[mt] = *(const bf16x8*)&VT[wm + 16 * mt + l15][32 * ks + 8 * g];
#pragma unroll
      for (int nt = 0; nt < 4; ++nt)
        bfr[nt] = *(const bf16x8*)&PT[wn + 16 * nt + l15][32 * ks + 8 * g];
#pragma unroll
      for (int mt = 0; mt < 4; ++mt)
#pragma unroll
        for (int nt = 0; nt < 4; ++nt)
          acc[mt][nt] = __builtin_amdgcn_mfma_f32_16x16x32_bf16(
              af[mt], bfr[nt], acc[mt][nt], 0, 0, 0);
    }
    __syncthreads();
  }
  const float gv = gamma[0];
  float rl[4];
#pragma unroll
  for (int nt = 0; nt < 4; ++nt)
    rl[nt] = 1.f / lsum[(size_t)b * NN + q0 + wn + 16 * nt + l15];
#pragma unroll
  for (int mt = 0; mt < 4; ++mt) {
    int c = c0 + wm + 16 * mt + 4 * g;
#pragma unroll
    for (int r = 0; r < 4; ++r) {
      size_t rowoff = ((size_t)b * CC + c + r) * NN;
#pragma unroll
      for (int nt = 0; nt < 4; ++nt) {
        size_t off = rowoff + q0 + wn + 16 * nt + l15;
        out[off] += gv * acc[mt][nt][r] * rl[nt] + X[off];
      }
    }
  }
}

extern "C" void kernel_launch(void* const* d_in, const int* in_sizes, int n_in,
                              void* d_out, int out_size, void* d_ws, size_t ws_size,
                              hipStream_t stream) {
  const float* x   = (const float*)d_in[0];
  const float* pwq = (const float*)d_in[1];
  const float* pbq = (const float*)d_in[2];
  const float* pwk = (const float*)d_in[3];
  const float* pbk = (const float*)d_in[4];
  const float* pwv = (const float*)d_in[5];
  const float* pbv = (const float*)d_in[6];
  const float* pgam= (const float*)d_in[7];
  const float* cwq = (const float*)d_in[8];
  const float* cbq = (const float*)d_in[9];
  const float* cwk = (const float*)d_in[10];
  const float* cbk = (const float*)d_in[11];
  const float* cwv = (const float*)d_in[12];
  const float* cbv = (const float*)d_in[13];
  const float* cgam= (const float*)d_in[14];
  float* out = (float*)d_out;

  const size_t SMALL = (size_t)BB * DD * NN;
  const size_t BIG   = (size_t)BB * CC * NN;
  u16* vbuf = (u16*)d_ws;                      // BIG: V [c][n] (PAM) or vT [n][c] (CAM)
  u16* qbuf = vbuf + BIG;                      // SMALL
  u16* kbuf = qbuf + SMALL;                    // SMALL
  float* eC = (float*)(kbuf + SMALL);          // BB*CC*CC f32
  u16* attnB = (u16*)(eC + (size_t)BB * CC * CC);  // BB*CC*CC bf16
  float* lsum = (float*)(attnB + (size_t)BB * CC * CC);
  u16* Pws = (u16*)(lsum + (size_t)BB * NN);
  size_t fixed = (size_t)((char*)Pws - (char*)d_ws);
  int NB = 1;
  if (ws_size >= fixed + 4ull * NN * NN * 2) NB = 4;
  else if (ws_size >= fixed + 2ull * NN * NN * 2) NB = 2;

  dim3 blk(256);
  // ---- CAM phase: d_out <- gamma_c*outC + x ----
  proj64_mfma_kernel<<<dim3(32, 1, BB), blk, 0, stream>>>(cwq, cbq, x, qbuf);
  proj64_mfma_kernel<<<dim3(32, 1, BB), blk, 0, stream>>>(cwk, cbk, x, kbuf);
  projVT_mfma_kernel<<<dim3(32, 4, BB), blk, 0, stream>>>(cwv, cbv, x, vbuf);
  cam_energy_mfma_kernel<<<dim3(4, 4, BB), blk, 0, stream>>>(qbuf, kbuf, eC);
  cam_softmax_kernel<<<dim3(CC, BB), blk, 0, stream>>>(eC, attnB);
  cam_gemm_kernel<<<dim3(32, 4, BB), blk, 0, stream>>>(attnB, vbuf, cgam, x, out);
  // ---- PAM phase: d_out += gamma_p*outP + x ----
  projT_mfma_kernel<<<dim3(32, 1, BB), blk, 0, stream>>>(pwq, pbq, x, qbuf);
  projT_mfma_kernel<<<dim3(32, 1, BB), blk, 0, stream>>>(pwk, pbk, x, kbuf);
  projV_mfma_kernel<<<dim3(32, 4, BB), blk, 0, stream>>>(pwv, pbv, x, vbuf);
  zero_kernel<<<dim3((BB * NN) / 256), blk, 0, stream>>>(lsum, BB * NN);
  for (int bb = 0; bb < BB; bb += NB) {
    pam_p_kernel<<<dim3(NN / 32, NN / KCH, NB), blk, 0, stream>>>(qbuf, kbuf, Pws, lsum, bb);
    pam_gemm_kernel<<<dim3(NN / 128, CC / 128, NB), blk, 0, stream>>>(
        vbuf, Pws, pgam, x, lsum, out, bb);
  }
}